// Round 1
// baseline (1151.981 us; speedup 1.0000x reference)
//
#include <hip/hip_runtime.h>
#include <math.h>

namespace {

constexpr int Bn = 16;    // batch
constexpr int NG = 1024;  // general tokens
constexpr int Cc = 768;   // channels
constexpr int Hh = 12;    // heads
constexpr int HD = 64;    // head dim
constexpr int Nn = 1026;  // total tokens (cls, box, general)
constexpr int NR = 18;    // rows we actually need: 0,1 + 16 routed

// ---------------- K1: LayerNorm (fp64 accumulation) ----------------
__global__ __launch_bounds__(256) void k_ln(
    const float* __restrict__ gen, const float* __restrict__ cls,
    const float* __restrict__ box, const float* __restrict__ gamma,
    const float* __restrict__ beta, float* __restrict__ x) {
  int blk = blockIdx.x;
  int b = blk / Nn, n = blk % Nn;
  const float* src = (n == 0) ? cls + (size_t)b * Cc
                   : (n == 1) ? box + (size_t)b * Cc
                              : gen + ((size_t)b * NG + (n - 2)) * Cc;
  int t = threadIdx.x;
  float v0 = src[t], v1 = src[t + 256], v2 = src[t + 512];
  __shared__ double red[8];
  double s = (double)v0 + (double)v1 + (double)v2;
  for (int o = 32; o > 0; o >>= 1) s += __shfl_down(s, o, 64);
  int wid = t >> 6, lid = t & 63;
  if (lid == 0) red[wid] = s;
  __syncthreads();
  if (t == 0) red[4] = (red[0] + red[1] + red[2] + red[3]) / Cc;
  __syncthreads();
  double mean = red[4];
  double d0 = (double)v0 - mean, d1 = (double)v1 - mean, d2 = (double)v2 - mean;
  double sq = d0 * d0 + d1 * d1 + d2 * d2;
  for (int o = 32; o > 0; o >>= 1) sq += __shfl_down(sq, o, 64);
  __syncthreads();
  if (lid == 0) red[wid] = sq;
  __syncthreads();
  if (t == 0) {
    double var = (red[0] + red[1] + red[2] + red[3]) / Cc;
    red[5] = 1.0 / sqrt(var + 1e-5);
  }
  __syncthreads();
  double rs = red[5];
  float* dst = x + ((size_t)b * Nn + n) * Cc;
  dst[t]       = (float)(d0 * rs * (double)gamma[t]       + (double)beta[t]);
  dst[t + 256] = (float)(d1 * rs * (double)gamma[t + 256] + (double)beta[t + 256]);
  dst[t + 512] = (float)(d2 * rs * (double)gamma[t + 512] + (double)beta[t + 512]);
}

// ---------------- K2: q rows 0,1 (fp64) ----------------
__global__ __launch_bounds__(256) void k_q01(
    const float* __restrict__ wqkv, const float* __restrict__ x,
    double* __restrict__ q01d) {
  int b = blockIdx.x >> 1, i = blockIdx.x & 1;
  __shared__ float xl[Cc];
  const float* xr = x + ((size_t)b * Nn + i) * Cc;
  for (int c = threadIdx.x; c < Cc; c += 256) xl[c] = xr[c];
  __syncthreads();
  for (int o = threadIdx.x; o < Cc; o += 256) {
    const float* wr = wqkv + (size_t)o * Cc;
    double a0 = 0, a1 = 0, a2 = 0, a3 = 0;
    for (int c = 0; c < Cc; c += 4) {
      a0 += (double)wr[c]     * (double)xl[c];
      a1 += (double)wr[c + 1] * (double)xl[c + 1];
      a2 += (double)wr[c + 2] * (double)xl[c + 2];
      a3 += (double)wr[c + 3] * (double)xl[c + 3];
    }
    q01d[((size_t)b * 2 + i) * Cc + o] = (a0 + a1) + (a2 + a3);
  }
}

// ---------------- K3: u rows 0,1 (fp64): u[i,h,c] = sum_d q[h*64+d] * Wk[h*64+d, c]
__global__ __launch_bounds__(256) void k_u01(
    const float* __restrict__ wqkv, const double* __restrict__ q01d,
    double* __restrict__ u01d) {
  int blk = blockIdx.x;
  int h = blk % Hh; int i = (blk / Hh) & 1; int b = blk / (2 * Hh);
  __shared__ double qh[HD];
  const double* q = q01d + ((size_t)b * 2 + i) * Cc + h * HD;
  for (int d = threadIdx.x; d < HD; d += 256) qh[d] = q[d];
  __syncthreads();
  const float* wk = wqkv + (size_t)Cc * Cc;
  for (int c = threadIdx.x; c < Cc; c += 256) {
    double acc = 0;
    for (int d = 0; d < HD; d++) acc += qh[d] * (double)wk[(size_t)(h * HD + d) * Cc + c];
    u01d[(((size_t)(b * 2 + i)) * Hh + h) * Cc + c] = acc;
  }
}

// ---------------- K4: routing logits rows 0,1 (fp64 GEMM-ish) ----------------
// grid (Bn, 5); t = pair(0..127) + 128*g, g = i; JT=256 j per block
__global__ __launch_bounds__(256) void k_rlogits(
    const double* __restrict__ u01d, const float* __restrict__ x,
    double* __restrict__ Ld) {
  int b = blockIdx.x, jt = blockIdx.y;
  int j0 = jt * 256;
  int t = threadIdx.x;
  int pl = t & 127;
  int g  = t >> 7;
  __shared__ float xtT[32][256];
  __shared__ double ut[24][32];
  double acc[12][2] = {};
  for (int c0 = 0; c0 < Cc; c0 += 32) {
    {
      int j = j0 + t;
      if (j < Nn) {
        const float* xr = x + ((size_t)b * Nn + j) * Cc + c0;
        #pragma unroll
        for (int k = 0; k < 32; k += 4) {
          float4 v = *(const float4*)(xr + k);
          xtT[k][t] = v.x; xtT[k + 1][t] = v.y; xtT[k + 2][t] = v.z; xtT[k + 3][t] = v.w;
        }
      } else {
        for (int k = 0; k < 32; k++) xtT[k][t] = 0.f;
      }
    }
    for (int idx = t; idx < 24 * 32; idx += 256) {
      int r = idx >> 5, cc = idx & 31;
      ut[r][cc] = u01d[(((size_t)(b * 2 + (r / 12))) * Hh + (r % 12)) * Cc + c0 + cc];
    }
    __syncthreads();
    for (int cc = 0; cc < 32; cc++) {
      float2 xv = *(const float2*)&xtT[cc][pl * 2];
      double x0 = (double)xv.x, x1 = (double)xv.y;
      #pragma unroll
      for (int h = 0; h < 12; h++) {
        double uv = ut[g * 12 + h][cc];
        acc[h][0] += uv * x0;
        acc[h][1] += uv * x1;
      }
    }
    __syncthreads();
  }
  for (int h = 0; h < 12; h++) {
    #pragma unroll
    for (int k = 0; k < 2; k++) {
      int j = j0 + pl * 2 + k;
      if (j < Nn) {
        double val = acc[h][k] * 0.125;
        if (g == 0 && j == 1) val = 0.0;   // attn[:,:,0,1] = 0
        if (g == 1 && j == 0) val = 0.0;   // attn[:,:,1,0] = 0
        Ld[(((size_t)(b * 2 + g)) * Hh + h) * Nn + j] = val;
      }
    }
  }
}

// ---------------- K5: softmax rows 0,1 (fp64 in-place; also write fp32 P) ----
__global__ __launch_bounds__(256) void k_rsoftmax(
    double* __restrict__ Ld, float* __restrict__ P) {
  int blk = blockIdx.x;
  int h = blk % Hh; int i = (blk / Hh) & 1; int b = blk / (2 * Hh);
  double* row = Ld + (size_t)blk * Nn;
  float* prow = P + (((size_t)b * NR + i) * Hh + h) * Nn;
  int t = threadIdx.x;
  __shared__ double sd[256];
  double mx = -1e300;
  for (int j = t; j < Nn; j += 256) mx = fmax(mx, row[j]);
  sd[t] = mx; __syncthreads();
  for (int st = 128; st > 0; st >>= 1) { if (t < st) sd[t] = fmax(sd[t], sd[t + st]); __syncthreads(); }
  mx = sd[0]; __syncthreads();
  double sum = 0;
  for (int j = t; j < Nn; j += 256) sum += exp(row[j] - mx);
  sd[t] = sum; __syncthreads();
  for (int st = 128; st > 0; st >>= 1) { if (t < st) sd[t] += sd[t + st]; __syncthreads(); }
  double inv = 1.0 / sd[0];
  for (int j = t; j < Nn; j += 256) {
    double p = exp(row[j] - mx) * inv;
    row[j] = p;
    prow[j] = (float)p;
  }
}

// ---------------- K6: head means -> sum_a, diff (fp64) ----------------
__global__ __launch_bounds__(256) void k_rsums(
    const double* __restrict__ Ld, double* __restrict__ suma,
    double* __restrict__ diffd) {
  int b = blockIdx.x;
  for (int jg = threadIdx.x; jg < NG; jg += 256) {
    int j = jg + 2;
    double cs = 0, bs = 0;
    for (int h = 0; h < Hh; h++) {
      cs += Ld[(((size_t)(b * 2 + 0)) * Hh + h) * Nn + j];
      bs += Ld[(((size_t)(b * 2 + 1)) * Hh + h) * Nn + j];
    }
    cs /= 12.0; bs /= 12.0;
    suma[(size_t)b * NG + jg] = cs + bs;
    diffd[(size_t)b * NG + jg] = bs - cs;
  }
}

// ---------------- K7: routing (replicates _route semantics) ----------------
__global__ __launch_bounds__(256) void k_route(
    const double* __restrict__ suma, const double* __restrict__ diffd,
    int* __restrict__ rowcat) {
  int b = blockIdx.x, t = threadIdx.x;
  __shared__ double vals[NG];
  __shared__ unsigned char isbox[NG];
  __shared__ unsigned char picked[NG];
  __shared__ double rv[256];
  __shared__ int ri[256];
  __shared__ int blist[16], clist[16];
  for (int j = t; j < NG; j += 256) {
    vals[j] = suma[(size_t)b * NG + j];
    isbox[j] = diffd[(size_t)b * NG + j] > 0.0 ? 1 : 0;
    picked[j] = 0;
  }
  __syncthreads();
  for (int cat = 0; cat < 2; cat++) {     // cat 0 = cls-preferred, 1 = box-preferred
    for (int s = 0; s < 16; s++) {
      double bv = -1e300; int bi = -1;
      for (int j = t; j < NG; j += 256) {
        if (isbox[j] == cat && !picked[j]) {
          if (vals[j] > bv || (vals[j] == bv && j < bi)) { bv = vals[j]; bi = j; }
        }
      }
      rv[t] = bv; ri[t] = bi;
      __syncthreads();
      for (int st = 128; st > 0; st >>= 1) {
        if (t < st) {
          if (ri[t + st] >= 0 &&
              (ri[t] < 0 || rv[t + st] > rv[t] ||
               (rv[t + st] == rv[t] && ri[t + st] < ri[t]))) {
            rv[t] = rv[t + st]; ri[t] = ri[t + st];
          }
        }
        __syncthreads();
      }
      if (t == 0) {
        int w = ri[0];
        if (cat) blist[s] = w; else clist[s] = w;
        if (w >= 0) picked[w] = 1;
      }
      __syncthreads();
    }
  }
  if (t < 16) {
    int s = t;
    int bc = blist[s];
    int cl = clist[15 - s];
    int win;
    if (bc < 0 && cl < 0) win = -1;
    else if (bc < 0) win = cl;
    else if (cl < 0) win = bc;
    else {
      // larger sorted position j wins => smaller sum wins (descending stable sort);
      // tie in sum => larger original index is later => wins
      bool boxwins = (vals[bc] < vals[cl]) || (vals[bc] == vals[cl] && bc > cl);
      win = boxwins ? bc : cl;
    }
    int tok = (win >= 0) ? win : 0;
    rowcat[b * NR + 2 + s] = tok + 2;   // cat-space token index
  }
  if (t == 0) { rowcat[b * NR + 0] = 0; rowcat[b * NR + 1] = 1; }
}

// ---------------- K8: q for 16 gathered rows (fp32) ----------------
__global__ __launch_bounds__(256) void k_qg(
    const float* __restrict__ wqkv, const float* __restrict__ x,
    const int* __restrict__ rowcat, float* __restrict__ qf) {
  int b = blockIdx.x >> 4, s = blockIdx.x & 15;
  int tok = rowcat[b * NR + 2 + s];
  __shared__ float xl[Cc];
  const float* xr = x + ((size_t)b * Nn + tok) * Cc;
  for (int c = threadIdx.x; c < Cc; c += 256) xl[c] = xr[c];
  __syncthreads();
  for (int o = threadIdx.x; o < Cc; o += 256) {
    const float* wr = wqkv + (size_t)o * Cc;
    float a0 = 0, a1 = 0, a2 = 0, a3 = 0;
    for (int c = 0; c < Cc; c += 4) {
      a0 += wr[c] * xl[c]; a1 += wr[c + 1] * xl[c + 1];
      a2 += wr[c + 2] * xl[c + 2]; a3 += wr[c + 3] * xl[c + 3];
    }
    qf[((size_t)b * NR + 2 + s) * Cc + o] = (a0 + a1) + (a2 + a3);
  }
}

// ---------------- K9: u for gathered rows (fp32, GEMM-tiled over Wk) -------
// grid (Hh, 6, 4): h, c-tile(128), bs-tile(64 of 256 rows)
__global__ __launch_bounds__(256) void k_ug(
    const float* __restrict__ wqkv, const float* __restrict__ qf,
    float* __restrict__ u16f) {
  int h = blockIdx.x, ct = blockIdx.y, bst = blockIdx.z;
  int t = threadIdx.x;
  int cq = t & 31, rg = t >> 5;
  int c0 = ct * 128;
  const float* wk = wqkv + (size_t)Cc * Cc + (size_t)h * HD * Cc;
  __shared__ float qt[64][17];
  __shared__ float wt[16][128];
  float acc[8][4] = {};
  for (int d0 = 0; d0 < HD; d0 += 16) {
    for (int idx = t; idx < 64 * 16; idx += 256) {
      int r = idx >> 4, dd = idx & 15;
      int bs = bst * 64 + r;
      int b = bs >> 4, s = bs & 15;
      qt[r][dd] = qf[((size_t)b * NR + 2 + s) * Cc + h * HD + d0 + dd];
    }
    for (int idx = t; idx < 16 * 128; idx += 256) {
      int dd = idx >> 7, cc = idx & 127;
      wt[dd][cc] = wk[(size_t)(d0 + dd) * Cc + c0 + cc];
    }
    __syncthreads();
    for (int dd = 0; dd < 16; dd++) {
      float4 wv = *(const float4*)&wt[dd][cq * 4];
      #pragma unroll
      for (int r = 0; r < 8; r++) {
        float qv = qt[rg * 8 + r][dd];
        acc[r][0] += qv * wv.x; acc[r][1] += qv * wv.y;
        acc[r][2] += qv * wv.z; acc[r][3] += qv * wv.w;
      }
    }
    __syncthreads();
  }
  for (int r = 0; r < 8; r++) {
    int bs = bst * 64 + rg * 8 + r;
    int b = bs >> 4, s = bs & 15;
    float* dst = u16f + (((size_t)b * 16 + s) * Hh + h) * Cc + c0 + cq * 4;
    *(float4*)dst = make_float4(acc[r][0], acc[r][1], acc[r][2], acc[r][3]);
  }
}

// ---------------- K10: gathered logits (fp32 GEMM-ish) ----------------
// grid (Bn, 4, 5): b, i-quad, j-tile(256). t = quad(0..63) + 64*g
__global__ __launch_bounds__(256) void k_glogits(
    const float* __restrict__ u16f, const float* __restrict__ x,
    float* __restrict__ P) {
  int b = blockIdx.x, iq = blockIdx.y, jt = blockIdx.z;
  int j0 = jt * 256;
  int t = threadIdx.x;
  int ql = t & 63;
  int g = t >> 6;
  int s = iq * 4 + g;
  __shared__ float xtT[32][256];
  __shared__ float ut[48][32];
  float acc[12][4] = {};
  for (int c0 = 0; c0 < Cc; c0 += 32) {
    {
      int j = j0 + t;
      if (j < Nn) {
        const float* xr = x + ((size_t)b * Nn + j) * Cc + c0;
        #pragma unroll
        for (int k = 0; k < 32; k += 4) {
          float4 v = *(const float4*)(xr + k);
          xtT[k][t] = v.x; xtT[k + 1][t] = v.y; xtT[k + 2][t] = v.z; xtT[k + 3][t] = v.w;
        }
      } else {
        for (int k = 0; k < 32; k++) xtT[k][t] = 0.f;
      }
    }
    for (int idx = t; idx < 48 * 32; idx += 256) {
      int r = idx >> 5, cc = idx & 31;
      int ss = iq * 4 + (r / 12), hh = r % 12;
      ut[r][cc] = u16f[(((size_t)b * 16 + ss) * Hh + hh) * Cc + c0 + cc];
    }
    __syncthreads();
    for (int cc = 0; cc < 32; cc++) {
      float4 xv = *(const float4*)&xtT[cc][ql * 4];
      #pragma unroll
      for (int h = 0; h < 12; h++) {
        float uv = ut[g * 12 + h][cc];
        acc[h][0] += uv * xv.x; acc[h][1] += uv * xv.y;
        acc[h][2] += uv * xv.z; acc[h][3] += uv * xv.w;
      }
    }
    __syncthreads();
  }
  for (int h = 0; h < 12; h++) {
    float* prow = P + (((size_t)b * NR + 2 + s) * Hh + h) * Nn;
    #pragma unroll
    for (int k = 0; k < 4; k++) {
      int j = j0 + ql * 4 + k;
      if (j < Nn) prow[j] = acc[h][k] * 0.125f;
    }
  }
}

// ---------------- K11: softmax for gathered rows (fp32, in-place) ----------
__global__ __launch_bounds__(256) void k_gsoftmax(float* __restrict__ P) {
  int blk = blockIdx.x;
  int h = blk % Hh; int s = (blk / Hh) & 15; int b = blk / (16 * Hh);
  float* row = P + (((size_t)b * NR + 2 + s) * Hh + h) * Nn;
  int t = threadIdx.x;
  __shared__ float sd[256];
  float mx = -1e30f;
  for (int j = t; j < Nn; j += 256) mx = fmaxf(mx, row[j]);
  sd[t] = mx; __syncthreads();
  for (int st = 128; st > 0; st >>= 1) { if (t < st) sd[t] = fmaxf(sd[t], sd[t + st]); __syncthreads(); }
  mx = sd[0]; __syncthreads();
  float sum = 0;
  for (int j = t; j < Nn; j += 256) sum += __expf(row[j] - mx);
  sd[t] = sum; __syncthreads();
  for (int st = 128; st > 0; st >>= 1) { if (t < st) sd[t] += sd[t + st]; __syncthreads(); }
  float inv = 1.0f / sd[0];
  for (int j = t; j < Nn; j += 256) row[j] = __expf(row[j] - mx) * inv;
}

// ---------------- K12: wsum[b,i,h,c] = sum_j P[b,i,h,j] * x[b,j,c] ---------
// grid (Bn, 9, 6): b, row-tile(24 of 216 (i,h) rows), c-tile(128)
__global__ __launch_bounds__(256) void k_wsum(
    const float* __restrict__ P, const float* __restrict__ x,
    float* __restrict__ wsumf) {
  int b = blockIdx.x, rt = blockIdx.y, ct = blockIdx.z;
  int t = threadIdx.x;
  int cq = t & 31;
  int rg = t >> 5;
  int c0 = ct * 128;
  __shared__ float xt[16][128];
  __shared__ float pt[24][17];
  float acc[3][4] = {};
  for (int jc = 0; jc < Nn; jc += 16) {
    for (int idx = t; idx < 16 * 128; idx += 256) {
      int jj = idx >> 7, ccc = idx & 127;
      int j = jc + jj;
      xt[jj][ccc] = (j < Nn) ? x[((size_t)b * Nn + j) * Cc + c0 + ccc] : 0.f;
    }
    for (int idx = t; idx < 24 * 16; idx += 256) {
      int r = idx >> 4, jj = idx & 15;
      int rglob = rt * 24 + r;
      int i = rglob / 12, h = rglob % 12;
      int j = jc + jj;
      pt[r][jj] = (j < Nn) ? P[(((size_t)b * NR + i) * Hh + h) * Nn + j] : 0.f;
    }
    __syncthreads();
    for (int jj = 0; jj < 16; jj++) {
      float4 xv = *(const float4*)&xt[jj][cq * 4];
      #pragma unroll
      for (int r = 0; r < 3; r++) {
        float pv = pt[rg * 3 + r][jj];
        acc[r][0] += pv * xv.x; acc[r][1] += pv * xv.y;
        acc[r][2] += pv * xv.z; acc[r][3] += pv * xv.w;
      }
    }
    __syncthreads();
  }
  for (int r = 0; r < 3; r++) {
    int rglob = rt * 24 + rg * 3 + r;
    int i = rglob / 12, h = rglob % 12;
    float* dst = wsumf + (((size_t)b * NR + i) * Hh + h) * Cc + c0 + cq * 4;
    *(float4*)dst = make_float4(acc[r][0], acc[r][1], acc[r][2], acc[r][3]);
  }
}

// ---------------- K13: attnout[bi, h*64+d] = sum_c Wv[h*64+d,c]*wsum[bi,h,c]
// grid (Hh, 6): h, bi-tile(48). t = d(0..63) + 64*bg
__global__ __launch_bounds__(256) void k_attnout(
    const float* __restrict__ wqkv, const float* __restrict__ wsumf,
    float* __restrict__ aof) {
  int h = blockIdx.x, bt = blockIdx.y;
  int t = threadIdx.x;
  int dl = t & 63, bg = t >> 6;
  const float* wv = wqkv + (size_t)2 * Cc * Cc;
  __shared__ float at[48][17];
  __shared__ float btile[64][17];
  float acc[12] = {};
  for (int c0 = 0; c0 < Cc; c0 += 16) {
    for (int idx = t; idx < 48 * 16; idx += 256) {
      int r = idx >> 4, cc = idx & 15;
      int bi = bt * 48 + r; int bb = bi / NR, ii = bi % NR;
      at[r][cc] = wsumf[(((size_t)bb * NR + ii) * Hh + h) * Cc + c0 + cc];
    }
    for (int idx = t; idx < 64 * 16; idx += 256) {
      int r = idx >> 4, cc = idx & 15;
      btile[r][cc] = wv[(size_t)(h * HD + r) * Cc + c0 + cc];
    }
    __syncthreads();
    for (int cc = 0; cc < 16; cc++) {
      float bv = btile[dl][cc];
      #pragma unroll
      for (int r = 0; r < 12; r++) acc[r] += at[bg * 12 + r][cc] * bv;
    }
    __syncthreads();
  }
  for (int r = 0; r < 12; r++) {
    int bi = bt * 48 + bg * 12 + r;
    aof[(size_t)bi * Cc + h * HD + dl] = acc[r];
  }
}

// ---------------- K14: proj + bias + residual + scatter to output ----------
// grid (6, 12): bi-tile(48), c-tile(64). t = cl(0..63) + 64*bg
__global__ __launch_bounds__(256) void k_proj(
    const float* __restrict__ wproj, const float* __restrict__ bproj,
    const float* __restrict__ aof, const int* __restrict__ rowcat,
    const float* __restrict__ gen, const float* __restrict__ cls,
    const float* __restrict__ box, float* __restrict__ out) {
  int bt = blockIdx.x, ct = blockIdx.y;
  int t = threadIdx.x;
  int cl = t & 63, bg = t >> 6;
  int c0 = ct * 64;
  __shared__ float at[48][17];
  __shared__ float btile[64][17];
  float acc[12] = {};
  for (int o0 = 0; o0 < Cc; o0 += 16) {
    for (int idx = t; idx < 48 * 16; idx += 256) {
      int r = idx >> 4, cc = idx & 15;
      at[r][cc] = aof[(size_t)(bt * 48 + r) * Cc + o0 + cc];
    }
    for (int idx = t; idx < 64 * 16; idx += 256) {
      int r = idx >> 4, cc = idx & 15;
      btile[r][cc] = wproj[(size_t)(c0 + r) * Cc + o0 + cc];
    }
    __syncthreads();
    for (int cc = 0; cc < 16; cc++) {
      float bv = btile[cl][cc];
      #pragma unroll
      for (int r = 0; r < 12; r++) acc[r] += at[bg * 12 + r][cc] * bv;
    }
    __syncthreads();
  }
  int c = c0 + cl;
  for (int r = 0; r < 12; r++) {
    int bi = bt * 48 + bg * 12 + r;
    int b = bi / NR, i = bi % NR;
    int tok = rowcat[b * NR + i];
    const float* src = (tok == 0) ? cls + (size_t)b * Cc
                     : (tok == 1) ? box + (size_t)b * Cc
                                  : gen + ((size_t)b * NG + tok - 2) * Cc;
    float val = acc[r] + bproj[c] + src[c];
    float* dst;
    if (i == 0)       dst = out + ((size_t)b * 9 + 0) * Cc;                       // cls_task row 0
    else if (i == 1)  dst = out + (size_t)Bn * 9 * Cc + ((size_t)b * 9 + 0) * Cc; // box_task row 0
    else if (i < 10)  dst = out + ((size_t)b * 9 + (i - 1)) * Cc;                 // cls_task rows 1..8
    else              dst = out + (size_t)Bn * 9 * Cc + ((size_t)b * 9 + (i - 9)) * Cc; // box_task 1..8
    dst[c] = val;
  }
}

}  // namespace

extern "C" void kernel_launch(void* const* d_in, const int* in_sizes, int n_in,
                              void* d_out, int out_size, void* d_ws, size_t ws_size,
                              hipStream_t stream) {
  (void)in_sizes; (void)n_in; (void)out_size; (void)ws_size;
  const float* gen   = (const float*)d_in[0];
  const float* cls   = (const float*)d_in[1];
  const float* box   = (const float*)d_in[2];
  const float* wqkv  = (const float*)d_in[3];
  const float* wproj = (const float*)d_in[4];
  const float* bproj = (const float*)d_in[5];
  const float* gamma = (const float*)d_in[6];
  const float* beta  = (const float*)d_in[7];
  float* out = (float*)d_out;

  char* ws = (char*)d_ws;
  size_t off = 0;
  auto alloc_f = [&](size_t n) { float* p = (float*)(ws + off); off += n * sizeof(float); return p; };
  float* x     = alloc_f((size_t)Bn * Nn * Cc);
  float* qf    = alloc_f((size_t)Bn * NR * Cc);
  float* u16f  = alloc_f((size_t)Bn * 16 * Hh * Cc);
  float* P     = alloc_f((size_t)Bn * NR * Hh * Nn);
  float* wsumf = alloc_f((size_t)Bn * NR * Hh * Cc);
  float* aof   = alloc_f((size_t)Bn * NR * Cc);
  auto alloc_d = [&](size_t n) { double* p = (double*)(ws + off); off += n * sizeof(double); return p; };
  double* q01d  = alloc_d((size_t)Bn * 2 * Cc);
  double* u01d  = alloc_d((size_t)Bn * 2 * Hh * Cc);
  double* Ld    = alloc_d((size_t)Bn * 2 * Hh * Nn);
  double* suma  = alloc_d((size_t)Bn * NG);
  double* diffd = alloc_d((size_t)Bn * NG);
  int* rowcat = (int*)(ws + off); off += (size_t)Bn * NR * sizeof(int);

  k_ln<<<Bn * Nn, 256, 0, stream>>>(gen, cls, box, gamma, beta, x);
  k_q01<<<Bn * 2, 256, 0, stream>>>(wqkv, x, q01d);
  k_u01<<<Bn * 2 * Hh, 256, 0, stream>>>(wqkv, q01d, u01d);
  k_rlogits<<<dim3(Bn, 5), 256, 0, stream>>>(u01d, x, Ld);
  k_rsoftmax<<<Bn * 2 * Hh, 256, 0, stream>>>(Ld, P);
  k_rsums<<<Bn, 256, 0, stream>>>(Ld, suma, diffd);
  k_route<<<Bn, 256, 0, stream>>>(suma, diffd, rowcat);
  k_qg<<<Bn * 16, 256, 0, stream>>>(wqkv, x, rowcat, qf);
  k_ug<<<dim3(Hh, 6, 4), 256, 0, stream>>>(wqkv, qf, u16f);
  k_glogits<<<dim3(Bn, 4, 5), 256, 0, stream>>>(u16f, x, P);
  k_gsoftmax<<<Bn * 16 * Hh, 256, 0, stream>>>(P);
  k_wsum<<<dim3(Bn, 9, 6), 256, 0, stream>>>(P, x, wsumf);
  k_attnout<<<dim3(Hh, 6), 256, 0, stream>>>(wqkv, wsumf, aof);
  k_proj<<<dim3(6, 12), 256, 0, stream>>>(wproj, bproj, aof, rowcat, gen, cls, box, out);
}

// Round 2
// 938.597 us; speedup vs baseline: 1.2273x; 1.2273x over previous
//
#include <hip/hip_runtime.h>
#include <math.h>

namespace {

constexpr int Bn = 16;    // batch
constexpr int NG = 1024;  // general tokens
constexpr int Cc = 768;   // channels
constexpr int Hh = 12;    // heads
constexpr int HD = 64;    // head dim
constexpr int Nn = 1026;  // total tokens (cls, box, general)
constexpr int NR = 18;    // rows we actually need: 0,1 + 16 routed
constexpr int NP = 1088;  // padded token count (17*64, mult of 32) for MFMA K / N

typedef __attribute__((ext_vector_type(8))) short short8;
typedef __attribute__((ext_vector_type(4))) float f32x4;

__device__ inline unsigned short f2bf(float f) {
  unsigned u = __float_as_uint(f);
  unsigned r = u + 0x7FFFu + ((u >> 16) & 1u);
  return (unsigned short)(r >> 16);
}

// ---------------- K1: LayerNorm (fp64 accumulation) ----------------
__global__ __launch_bounds__(256) void k_ln(
    const float* __restrict__ gen, const float* __restrict__ cls,
    const float* __restrict__ box, const float* __restrict__ gamma,
    const float* __restrict__ beta, float* __restrict__ x,
    unsigned short* __restrict__ xbf) {
  int blk = blockIdx.x;
  int b = blk / Nn, n = blk % Nn;
  const float* src = (n == 0) ? cls + (size_t)b * Cc
                   : (n == 1) ? box + (size_t)b * Cc
                              : gen + ((size_t)b * NG + (n - 2)) * Cc;
  int t = threadIdx.x;
  float v0 = src[t], v1 = src[t + 256], v2 = src[t + 512];
  __shared__ double red[8];
  double s = (double)v0 + (double)v1 + (double)v2;
  for (int o = 32; o > 0; o >>= 1) s += __shfl_down(s, o, 64);
  int wid = t >> 6, lid = t & 63;
  if (lid == 0) red[wid] = s;
  __syncthreads();
  if (t == 0) red[4] = (red[0] + red[1] + red[2] + red[3]) / Cc;
  __syncthreads();
  double mean = red[4];
  double d0 = (double)v0 - mean, d1 = (double)v1 - mean, d2 = (double)v2 - mean;
  double sq = d0 * d0 + d1 * d1 + d2 * d2;
  for (int o = 32; o > 0; o >>= 1) sq += __shfl_down(sq, o, 64);
  __syncthreads();
  if (lid == 0) red[wid] = sq;
  __syncthreads();
  if (t == 0) {
    double var = (red[0] + red[1] + red[2] + red[3]) / Cc;
    red[5] = 1.0 / sqrt(var + 1e-5);
  }
  __syncthreads();
  double rs = red[5];
  float* dst = x + ((size_t)b * Nn + n) * Cc;
  unsigned short* dbf = xbf + ((size_t)b * NP + n) * Cc;
  float o0 = (float)(d0 * rs * (double)gamma[t]       + (double)beta[t]);
  float o1 = (float)(d1 * rs * (double)gamma[t + 256] + (double)beta[t + 256]);
  float o2 = (float)(d2 * rs * (double)gamma[t + 512] + (double)beta[t + 512]);
  dst[t] = o0; dst[t + 256] = o1; dst[t + 512] = o2;
  dbf[t] = f2bf(o0); dbf[t + 256] = f2bf(o1); dbf[t + 512] = f2bf(o2);
}

// ---------------- K1b: zero pad rows 1026..1087 of x_bf ----------------
__global__ __launch_bounds__(256) void k_padzero(unsigned short* __restrict__ xbf) {
  constexpr int PERB = (NP - Nn) * Cc / 2;  // uints per batch
  int idx = blockIdx.x * 256 + threadIdx.x;
  int total = Bn * PERB;
  for (int i = idx; i < total; i += gridDim.x * 256) {
    int b = i / PERB, r = i % PERB;
    unsigned int* p = (unsigned int*)(xbf + ((size_t)b * NP + Nn) * Cc);
    p[r] = 0u;
  }
}

// ---------------- K1c: transpose x_bf -> xT_bf [b][c][jpad] ----------------
__global__ __launch_bounds__(256) void k_xt(
    const unsigned short* __restrict__ xbf, unsigned short* __restrict__ xT) {
  int b = blockIdx.x, jt = blockIdx.y, ct = blockIdx.z;
  int j0 = jt * 64, c0 = ct * 64;
  __shared__ unsigned short ts[64][80];
  int t = threadIdx.x;
  #pragma unroll
  for (int l = 0; l < 2; l++) {
    int chunk = t + l * 256;
    int r = chunk >> 3, c8 = chunk & 7;
    uint4 v = *(const uint4*)(xbf + ((size_t)b * NP + j0 + r) * Cc + c0 + c8 * 8);
    *(uint4*)&ts[r][c8 * 8] = v;
  }
  __syncthreads();
  #pragma unroll
  for (int l = 0; l < 2; l++) {
    int chunk = t + l * 256;
    int orow = chunk >> 3, j8 = chunk & 7;
    unsigned short tmp[8];
    #pragma unroll
    for (int i = 0; i < 8; i++) tmp[i] = ts[j8 * 8 + i][orow];
    *(uint4*)(xT + ((size_t)b * Cc + c0 + orow) * NP + j0 + j8 * 8) = *(uint4*)tmp;
  }
}

// ---------------- K2: q rows 0,1 (fp64) ----------------
__global__ __launch_bounds__(256) void k_q01(
    const float* __restrict__ wqkv, const float* __restrict__ x,
    double* __restrict__ q01d) {
  int b = blockIdx.x >> 1, i = blockIdx.x & 1;
  __shared__ float xl[Cc];
  const float* xr = x + ((size_t)b * Nn + i) * Cc;
  for (int c = threadIdx.x; c < Cc; c += 256) xl[c] = xr[c];
  __syncthreads();
  for (int o = threadIdx.x; o < Cc; o += 256) {
    const float* wr = wqkv + (size_t)o * Cc;
    double a0 = 0, a1 = 0, a2 = 0, a3 = 0;
    for (int c = 0; c < Cc; c += 4) {
      a0 += (double)wr[c]     * (double)xl[c];
      a1 += (double)wr[c + 1] * (double)xl[c + 1];
      a2 += (double)wr[c + 2] * (double)xl[c + 2];
      a3 += (double)wr[c + 3] * (double)xl[c + 3];
    }
    q01d[((size_t)b * 2 + i) * Cc + o] = (a0 + a1) + (a2 + a3);
  }
}

// ---------------- K3: u rows 0,1 (fp64) ----------------
__global__ __launch_bounds__(256) void k_u01(
    const float* __restrict__ wqkv, const double* __restrict__ q01d,
    double* __restrict__ u01d) {
  int blk = blockIdx.x;
  int h = blk % Hh; int i = (blk / Hh) & 1; int b = blk / (2 * Hh);
  __shared__ double qh[HD];
  const double* q = q01d + ((size_t)b * 2 + i) * Cc + h * HD;
  for (int d = threadIdx.x; d < HD; d += 256) qh[d] = q[d];
  __syncthreads();
  const float* wk = wqkv + (size_t)Cc * Cc;
  for (int c = threadIdx.x; c < Cc; c += 256) {
    double acc = 0;
    for (int d = 0; d < HD; d++) acc += qh[d] * (double)wk[(size_t)(h * HD + d) * Cc + c];
    u01d[(((size_t)(b * 2 + i)) * Hh + h) * Cc + c] = acc;
  }
}

// ---------------- K4: routing logits rows 0,1 (fp64) ----------------
__global__ __launch_bounds__(256) void k_rlogits(
    const double* __restrict__ u01d, const float* __restrict__ x,
    double* __restrict__ Ld) {
  int b = blockIdx.x, jt = blockIdx.y;
  int j0 = jt * 256;
  int t = threadIdx.x;
  int pl = t & 127;
  int g  = t >> 7;
  __shared__ float xtT[32][256];
  __shared__ double ut[24][32];
  double acc[12][2] = {};
  for (int c0 = 0; c0 < Cc; c0 += 32) {
    {
      int j = j0 + t;
      if (j < Nn) {
        const float* xr = x + ((size_t)b * Nn + j) * Cc + c0;
        #pragma unroll
        for (int k = 0; k < 32; k += 4) {
          float4 v = *(const float4*)(xr + k);
          xtT[k][t] = v.x; xtT[k + 1][t] = v.y; xtT[k + 2][t] = v.z; xtT[k + 3][t] = v.w;
        }
      } else {
        for (int k = 0; k < 32; k++) xtT[k][t] = 0.f;
      }
    }
    for (int idx = t; idx < 24 * 32; idx += 256) {
      int r = idx >> 5, cc = idx & 31;
      ut[r][cc] = u01d[(((size_t)(b * 2 + (r / 12))) * Hh + (r % 12)) * Cc + c0 + cc];
    }
    __syncthreads();
    for (int cc = 0; cc < 32; cc++) {
      float2 xv = *(const float2*)&xtT[cc][pl * 2];
      double x0 = (double)xv.x, x1 = (double)xv.y;
      #pragma unroll
      for (int h = 0; h < 12; h++) {
        double uv = ut[g * 12 + h][cc];
        acc[h][0] += uv * x0;
        acc[h][1] += uv * x1;
      }
    }
    __syncthreads();
  }
  for (int h = 0; h < 12; h++) {
    #pragma unroll
    for (int k = 0; k < 2; k++) {
      int j = j0 + pl * 2 + k;
      if (j < Nn) {
        double val = acc[h][k] * 0.125;
        if (g == 0 && j == 1) val = 0.0;
        if (g == 1 && j == 0) val = 0.0;
        Ld[(((size_t)(b * 2 + g)) * Hh + h) * Nn + j] = val;
      }
    }
  }
}

// ---------------- K5: softmax rows 0,1 (fp64; writes bf16 P rows) ----------
__global__ __launch_bounds__(256) void k_rsoftmax(
    double* __restrict__ Ld, unsigned short* __restrict__ Pb) {
  int blk = blockIdx.x;
  int h = blk % Hh; int i = (blk / Hh) & 1; int b = blk / (2 * Hh);
  double* row = Ld + (size_t)blk * Nn;
  unsigned short* prow = Pb + ((size_t)b * 216 + i * Hh + h) * NP;
  int t = threadIdx.x;
  __shared__ double sd[256];
  double mx = -1e300;
  for (int j = t; j < Nn; j += 256) mx = fmax(mx, row[j]);
  sd[t] = mx; __syncthreads();
  for (int st = 128; st > 0; st >>= 1) { if (t < st) sd[t] = fmax(sd[t], sd[t + st]); __syncthreads(); }
  mx = sd[0]; __syncthreads();
  double sum = 0;
  for (int j = t; j < Nn; j += 256) sum += exp(row[j] - mx);
  sd[t] = sum; __syncthreads();
  for (int st = 128; st > 0; st >>= 1) { if (t < st) sd[t] += sd[t + st]; __syncthreads(); }
  double inv = 1.0 / sd[0];
  for (int j = t; j < NP; j += 256) {
    if (j < Nn) {
      double p = exp(row[j] - mx) * inv;
      row[j] = p;
      prow[j] = f2bf((float)p);
    } else {
      prow[j] = 0;
    }
  }
}

// ---------------- K6: head means -> sum_a, diff (fp64) ----------------
__global__ __launch_bounds__(256) void k_rsums(
    const double* __restrict__ Ld, double* __restrict__ suma,
    double* __restrict__ diffd) {
  int b = blockIdx.x;
  for (int jg = threadIdx.x; jg < NG; jg += 256) {
    int j = jg + 2;
    double cs = 0, bs = 0;
    for (int h = 0; h < Hh; h++) {
      cs += Ld[(((size_t)(b * 2 + 0)) * Hh + h) * Nn + j];
      bs += Ld[(((size_t)(b * 2 + 1)) * Hh + h) * Nn + j];
    }
    cs /= 12.0; bs /= 12.0;
    suma[(size_t)b * NG + jg] = cs + bs;
    diffd[(size_t)b * NG + jg] = bs - cs;
  }
}

// ---------------- K7: routing ----------------
__global__ __launch_bounds__(256) void k_route(
    const double* __restrict__ suma, const double* __restrict__ diffd,
    int* __restrict__ rowcat) {
  int b = blockIdx.x, t = threadIdx.x;
  __shared__ double vals[NG];
  __shared__ unsigned char isbox[NG];
  __shared__ unsigned char picked[NG];
  __shared__ double rv[256];
  __shared__ int ri[256];
  __shared__ int blist[16], clist[16];
  for (int j = t; j < NG; j += 256) {
    vals[j] = suma[(size_t)b * NG + j];
    isbox[j] = diffd[(size_t)b * NG + j] > 0.0 ? 1 : 0;
    picked[j] = 0;
  }
  __syncthreads();
  for (int cat = 0; cat < 2; cat++) {
    for (int s = 0; s < 16; s++) {
      double bv = -1e300; int bi = -1;
      for (int j = t; j < NG; j += 256) {
        if (isbox[j] == cat && !picked[j]) {
          if (vals[j] > bv || (vals[j] == bv && j < bi)) { bv = vals[j]; bi = j; }
        }
      }
      rv[t] = bv; ri[t] = bi;
      __syncthreads();
      for (int st = 128; st > 0; st >>= 1) {
        if (t < st) {
          if (ri[t + st] >= 0 &&
              (ri[t] < 0 || rv[t + st] > rv[t] ||
               (rv[t + st] == rv[t] && ri[t + st] < ri[t]))) {
            rv[t] = rv[t + st]; ri[t] = ri[t + st];
          }
        }
        __syncthreads();
      }
      if (t == 0) {
        int w = ri[0];
        if (cat) blist[s] = w; else clist[s] = w;
        if (w >= 0) picked[w] = 1;
      }
      __syncthreads();
    }
  }
  if (t < 16) {
    int s = t;
    int bc = blist[s];
    int cl = clist[15 - s];
    int win;
    if (bc < 0 && cl < 0) win = -1;
    else if (bc < 0) win = cl;
    else if (cl < 0) win = bc;
    else {
      bool boxwins = (vals[bc] < vals[cl]) || (vals[bc] == vals[cl] && bc > cl);
      win = boxwins ? bc : cl;
    }
    int tok = (win >= 0) ? win : 0;
    rowcat[b * NR + 2 + s] = tok + 2;
  }
  if (t == 0) { rowcat[b * NR + 0] = 0; rowcat[b * NR + 1] = 1; }
}

// ---------------- K8: q for 16 gathered rows (fp32) ----------------
__global__ __launch_bounds__(256) void k_qg(
    const float* __restrict__ wqkv, const float* __restrict__ x,
    const int* __restrict__ rowcat, float* __restrict__ qf) {
  int b = blockIdx.x >> 4, s = blockIdx.x & 15;
  int tok = rowcat[b * NR + 2 + s];
  __shared__ float xl[Cc];
  const float* xr = x + ((size_t)b * Nn + tok) * Cc;
  for (int c = threadIdx.x; c < Cc; c += 256) xl[c] = xr[c];
  __syncthreads();
  for (int o = threadIdx.x; o < Cc; o += 256) {
    const float* wr = wqkv + (size_t)o * Cc;
    float a0 = 0, a1 = 0, a2 = 0, a3 = 0;
    for (int c = 0; c < Cc; c += 4) {
      a0 += wr[c] * xl[c]; a1 += wr[c + 1] * xl[c + 1];
      a2 += wr[c + 2] * xl[c + 2]; a3 += wr[c + 3] * xl[c + 3];
    }
    qf[((size_t)b * NR + 2 + s) * Cc + o] = (a0 + a1) + (a2 + a3);
  }
}

// ---------------- K9: u for gathered rows (fp32 compute, bf16 store) -------
__global__ __launch_bounds__(256) void k_ug(
    const float* __restrict__ wqkv, const float* __restrict__ qf,
    unsigned short* __restrict__ u16b) {
  int h = blockIdx.x, ct = blockIdx.y, bst = blockIdx.z;
  int t = threadIdx.x;
  int cq = t & 31, rg = t >> 5;
  int c0 = ct * 128;
  const float* wk = wqkv + (size_t)Cc * Cc + (size_t)h * HD * Cc;
  __shared__ float qt[64][17];
  __shared__ float wt[16][128];
  float acc[8][4] = {};
  for (int d0 = 0; d0 < HD; d0 += 16) {
    for (int idx = t; idx < 64 * 16; idx += 256) {
      int r = idx >> 4, dd = idx & 15;
      int bs = bst * 64 + r;
      int b = bs >> 4, s = bs & 15;
      qt[r][dd] = qf[((size_t)b * NR + 2 + s) * Cc + h * HD + d0 + dd];
    }
    for (int idx = t; idx < 16 * 128; idx += 256) {
      int dd = idx >> 7, cc = idx & 127;
      wt[dd][cc] = wk[(size_t)(d0 + dd) * Cc + c0 + cc];
    }
    __syncthreads();
    for (int dd = 0; dd < 16; dd++) {
      float4 wv = *(const float4*)&wt[dd][cq * 4];
      #pragma unroll
      for (int r = 0; r < 8; r++) {
        float qv = qt[rg * 8 + r][dd];
        acc[r][0] += qv * wv.x; acc[r][1] += qv * wv.y;
        acc[r][2] += qv * wv.z; acc[r][3] += qv * wv.w;
      }
    }
    __syncthreads();
  }
  for (int r = 0; r < 8; r++) {
    int bs = bst * 64 + rg * 8 + r;
    int b = bs >> 4, s = bs & 15;
    unsigned short* dst = u16b + ((size_t)b * 192 + s * Hh + h) * Cc + c0 + cq * 4;
    ushort4 o;
    o.x = f2bf(acc[r][0]); o.y = f2bf(acc[r][1]);
    o.z = f2bf(acc[r][2]); o.w = f2bf(acc[r][3]);
    *(ushort4*)dst = o;
  }
}

// ---------------- K10: gathered logits via MFMA ----------------
// grid (Bn, 3, 13): b, m-group (4 waves -> 12 m-tiles), n-chunk (5 j-tiles)
__global__ __launch_bounds__(256) void k_glogits_mfma(
    const unsigned short* __restrict__ u16b, const unsigned short* __restrict__ xbf,
    float* __restrict__ S) {
  int b = blockIdx.x, mg = blockIdx.y, nz = blockIdx.z;
  int wid = threadIdx.x >> 6, lane = threadIdx.x & 63;
  int mtile = mg * 4 + wid;        // 0..11
  int m = lane & 15, kg = lane >> 4;
  int row = mtile * 16 + m;        // 0..191 (always valid)
  const unsigned short* abase = u16b + ((size_t)b * 192 + row) * Cc + kg * 8;
  const unsigned short* bbase = xbf + (size_t)b * NP * Cc + kg * 8;
  f32x4 acc[5] = {{0,0,0,0},{0,0,0,0},{0,0,0,0},{0,0,0,0},{0,0,0,0}};
  int jb = nz * 80 + m;
  for (int k0 = 0; k0 < Cc; k0 += 32) {
    short8 a = *(const short8*)(abase + k0);
    #pragma unroll
    for (int t = 0; t < 5; t++) {
      short8 bf = *(const short8*)(bbase + (size_t)(jb + t * 16) * Cc + k0);
      acc[t] = __builtin_amdgcn_mfma_f32_16x16x32_bf16(a, bf, acc[t], 0, 0, 0);
    }
  }
  #pragma unroll
  for (int t = 0; t < 5; t++) {
    int col = nz * 80 + t * 16 + m;
    #pragma unroll
    for (int r = 0; r < 4; r++) {
      int rr = mtile * 16 + kg * 4 + r;
      S[((size_t)b * 192 + rr) * 1040 + col] = acc[t][r] * 0.125f;
    }
  }
}

// ---------------- K11: softmax for gathered rows (reads S, writes bf16 P) --
__global__ __launch_bounds__(256) void k_gsoftmax(
    const float* __restrict__ S, unsigned short* __restrict__ Pb) {
  int blk = blockIdx.x;              // b*192 + r, r = s*12+h
  int b = blk / 192, r = blk % 192;
  const float* row = S + ((size_t)b * 192 + r) * 1040;
  unsigned short* prow = Pb + ((size_t)b * 216 + 24 + r) * NP;
  int t = threadIdx.x;
  __shared__ float sd[256];
  float mx = -1e30f;
  for (int j = t; j < Nn; j += 256) mx = fmaxf(mx, row[j]);
  sd[t] = mx; __syncthreads();
  for (int st = 128; st > 0; st >>= 1) { if (t < st) sd[t] = fmaxf(sd[t], sd[t + st]); __syncthreads(); }
  mx = sd[0]; __syncthreads();
  float sum = 0;
  for (int j = t; j < Nn; j += 256) sum += __expf(row[j] - mx);
  sd[t] = sum; __syncthreads();
  for (int st = 128; st > 0; st >>= 1) { if (t < st) sd[t] += sd[t + st]; __syncthreads(); }
  float inv = 1.0f / sd[0];
  for (int j = t; j < NP; j += 256) {
    prow[j] = (j < Nn) ? f2bf(__expf(row[j] - mx) * inv) : (unsigned short)0;
  }
}

// ---------------- K12: wsum via MFMA ----------------
// grid (Bn, 4, 8): b, m-group (4 waves -> 16 m-tiles of 14 used), n-chunk (6 c-tiles)
__global__ __launch_bounds__(256) void k_wsum_mfma(
    const unsigned short* __restrict__ Pb, const unsigned short* __restrict__ xT,
    float* __restrict__ wsumf) {
  int b = blockIdx.x, mg = blockIdx.y, nz = blockIdx.z;
  int wid = threadIdx.x >> 6, lane = threadIdx.x & 63;
  int mtile = mg * 4 + wid;        // 0..15
  int m = lane & 15, kg = lane >> 4;
  int row = mtile * 16 + m;
  int rowc = row < 216 ? row : 215;
  const unsigned short* abase = Pb + ((size_t)b * 216 + rowc) * NP + kg * 8;
  const unsigned short* bbase = xT + (size_t)b * Cc * NP + kg * 8;
  f32x4 acc[6] = {{0,0,0,0},{0,0,0,0},{0,0,0,0},{0,0,0,0},{0,0,0,0},{0,0,0,0}};
  int cb = nz * 96 + m;
  for (int k0 = 0; k0 < NP; k0 += 32) {
    short8 a = *(const short8*)(abase + k0);
    #pragma unroll
    for (int t = 0; t < 6; t++) {
      short8 bf = *(const short8*)(bbase + (size_t)(cb + t * 16) * NP + k0);
      acc[t] = __builtin_amdgcn_mfma_f32_16x16x32_bf16(a, bf, acc[t], 0, 0, 0);
    }
  }
  #pragma unroll
  for (int t = 0; t < 6; t++) {
    int col = nz * 96 + t * 16 + m;
    #pragma unroll
    for (int r = 0; r < 4; r++) {
      int rr = mtile * 16 + kg * 4 + r;
      if (rr < 216) wsumf[((size_t)b * 216 + rr) * Cc + col] = acc[t][r];
    }
  }
}

// ---------------- K13: attnout = Wv * wsum ----------------
__global__ __launch_bounds__(256) void k_attnout(
    const float* __restrict__ wqkv, const float* __restrict__ wsumf,
    float* __restrict__ aof) {
  int h = blockIdx.x, bt = blockIdx.y;
  int t = threadIdx.x;
  int dl = t & 63, bg = t >> 6;
  const float* wv = wqkv + (size_t)2 * Cc * Cc;
  __shared__ float at[48][17];
  __shared__ float btile[64][17];
  float acc[12] = {};
  for (int c0 = 0; c0 < Cc; c0 += 16) {
    for (int idx = t; idx < 48 * 16; idx += 256) {
      int r = idx >> 4, cc = idx & 15;
      int bi = bt * 48 + r; int bb = bi / NR, ii = bi % NR;
      at[r][cc] = wsumf[(((size_t)bb * NR + ii) * Hh + h) * Cc + c0 + cc];
    }
    for (int idx = t; idx < 64 * 16; idx += 256) {
      int r = idx >> 4, cc = idx & 15;
      btile[r][cc] = wv[(size_t)(h * HD + r) * Cc + c0 + cc];
    }
    __syncthreads();
    for (int cc = 0; cc < 16; cc++) {
      float bv = btile[dl][cc];
      #pragma unroll
      for (int r = 0; r < 12; r++) acc[r] += at[bg * 12 + r][cc] * bv;
    }
    __syncthreads();
  }
  for (int r = 0; r < 12; r++) {
    int bi = bt * 48 + bg * 12 + r;
    aof[(size_t)bi * Cc + h * HD + dl] = acc[r];
  }
}

// ---------------- K14: proj + bias + residual + scatter ----------------
__global__ __launch_bounds__(256) void k_proj(
    const float* __restrict__ wproj, const float* __restrict__ bproj,
    const float* __restrict__ aof, const int* __restrict__ rowcat,
    const float* __restrict__ gen, const float* __restrict__ cls,
    const float* __restrict__ box, float* __restrict__ out) {
  int bt = blockIdx.x, ct = blockIdx.y;
  int t = threadIdx.x;
  int cl = t & 63, bg = t >> 6;
  int c0 = ct * 64;
  __shared__ float at[48][17];
  __shared__ float btile[64][17];
  float acc[12] = {};
  for (int o0 = 0; o0 < Cc; o0 += 16) {
    for (int idx = t; idx < 48 * 16; idx += 256) {
      int r = idx >> 4, cc = idx & 15;
      at[r][cc] = aof[(size_t)(bt * 48 + r) * Cc + o0 + cc];
    }
    for (int idx = t; idx < 64 * 16; idx += 256) {
      int r = idx >> 4, cc = idx & 15;
      btile[r][cc] = wproj[(size_t)(c0 + r) * Cc + o0 + cc];
    }
    __syncthreads();
    for (int cc = 0; cc < 16; cc++) {
      float bv = btile[cl][cc];
      #pragma unroll
      for (int r = 0; r < 12; r++) acc[r] += at[bg * 12 + r][cc] * bv;
    }
    __syncthreads();
  }
  int c = c0 + cl;
  for (int r = 0; r < 12; r++) {
    int bi = bt * 48 + bg * 12 + r;
    int b = bi / NR, i = bi % NR;
    int tok = rowcat[b * NR + i];
    const float* src = (tok == 0) ? cls + (size_t)b * Cc
                     : (tok == 1) ? box + (size_t)b * Cc
                                  : gen + ((size_t)b * NG + tok - 2) * Cc;
    float val = acc[r] + bproj[c] + src[c];
    float* dst;
    if (i == 0)       dst = out + ((size_t)b * 9 + 0) * Cc;
    else if (i == 1)  dst = out + (size_t)Bn * 9 * Cc + ((size_t)b * 9 + 0) * Cc;
    else if (i < 10)  dst = out + ((size_t)b * 9 + (i - 1)) * Cc;
    else              dst = out + (size_t)Bn * 9 * Cc + ((size_t)b * 9 + (i - 9)) * Cc;
    dst[c] = val;
  }
}

}  // namespace

extern "C" void kernel_launch(void* const* d_in, const int* in_sizes, int n_in,
                              void* d_out, int out_size, void* d_ws, size_t ws_size,
                              hipStream_t stream) {
  (void)in_sizes; (void)n_in; (void)out_size; (void)ws_size;
  const float* gen   = (const float*)d_in[0];
  const float* cls   = (const float*)d_in[1];
  const float* box   = (const float*)d_in[2];
  const float* wqkv  = (const float*)d_in[3];
  const float* wproj = (const float*)d_in[4];
  const float* bproj = (const float*)d_in[5];
  const float* gamma = (const float*)d_in[6];
  const float* beta  = (const float*)d_in[7];
  float* out = (float*)d_out;

  char* ws = (char*)d_ws;
  size_t off = 0;
  auto alloc = [&](size_t bytes) { void* p = ws + off; off += (bytes + 255) & ~(size_t)255; return p; };
  float* x             = (float*)alloc((size_t)Bn * Nn * Cc * 4);
  unsigned short* xbf  = (unsigned short*)alloc((size_t)Bn * NP * Cc * 2);
  unsigned short* xT   = (unsigned short*)alloc((size_t)Bn * Cc * NP * 2);
  float* qf            = (float*)alloc((size_t)Bn * NR * Cc * 4);
  unsigned short* u16b = (unsigned short*)alloc((size_t)Bn * 192 * Cc * 2);
  float* S             = (float*)alloc((size_t)Bn * 192 * 1040 * 4);
  unsigned short* Pb   = (unsigned short*)alloc((size_t)Bn * 216 * NP * 2);
  float* wsumf         = (float*)alloc((size_t)Bn * 216 * Cc * 4);
  float* aof           = (float*)alloc((size_t)Bn * NR * Cc * 4);
  double* q01d         = (double*)alloc((size_t)Bn * 2 * Cc * 8);
  double* u01d         = (double*)alloc((size_t)Bn * 2 * Hh * Cc * 8);
  double* Ld           = (double*)alloc((size_t)Bn * 2 * Hh * Nn * 8);
  double* suma         = (double*)alloc((size_t)Bn * NG * 8);
  double* diffd        = (double*)alloc((size_t)Bn * NG * 8);
  int* rowcat          = (int*)alloc((size_t)Bn * NR * 4);

  k_ln<<<Bn * Nn, 256, 0, stream>>>(gen, cls, box, gamma, beta, x, xbf);
  k_padzero<<<48, 256, 0, stream>>>(xbf);
  k_xt<<<dim3(Bn, 17, 12), 256, 0, stream>>>(xbf, xT);
  k_q01<<<Bn * 2, 256, 0, stream>>>(wqkv, x, q01d);
  k_u01<<<Bn * 2 * Hh, 256, 0, stream>>>(wqkv, q01d, u01d);
  k_rlogits<<<dim3(Bn, 5), 256, 0, stream>>>(u01d, x, Ld);
  k_rsoftmax<<<Bn * 2 * Hh, 256, 0, stream>>>(Ld, Pb);
  k_rsums<<<Bn, 256, 0, stream>>>(Ld, suma, diffd);
  k_route<<<Bn, 256, 0, stream>>>(suma, diffd, rowcat);
  k_qg<<<Bn * 16, 256, 0, stream>>>(wqkv, x, rowcat, qf);
  k_ug<<<dim3(Hh, 6, 4), 256, 0, stream>>>(wqkv, qf, u16b);
  k_glogits_mfma<<<dim3(Bn, 3, 13), 256, 0, stream>>>(u16b, xbf, S);
  k_gsoftmax<<<Bn * 192, 256, 0, stream>>>(S, Pb);
  k_wsum_mfma<<<dim3(Bn, 4, 8), 256, 0, stream>>>(Pb, xT, wsumf);
  k_attnout<<<dim3(Hh, 6), 256, 0, stream>>>(wqkv, wsumf, aof);
  k_proj<<<dim3(6, 12), 256, 0, stream>>>(wproj, bproj, aof, rowcat, gen, cls, box, out);
}

// Round 3
// 607.176 us; speedup vs baseline: 1.8973x; 1.5458x over previous
//
#include <hip/hip_runtime.h>
#include <math.h>

namespace {

constexpr int Bn = 16;    // batch
constexpr int NG = 1024;  // general tokens
constexpr int Cc = 768;   // channels
constexpr int Hh = 12;    // heads
constexpr int HD = 64;    // head dim
constexpr int Nn = 1026;  // total tokens (cls, box, general)
constexpr int NR = 18;    // rows we actually need: 0,1 + 16 routed
constexpr int NP = 1088;  // padded token count (17*64) for MFMA K / N

typedef __attribute__((ext_vector_type(8))) short short8;
typedef __attribute__((ext_vector_type(4))) float f32x4;

__device__ inline unsigned short f2bf(float f) {
  unsigned u = __float_as_uint(f);
  unsigned r = u + 0x7FFFu + ((u >> 16) & 1u);
  return (unsigned short)(r >> 16);
}

// ---------------- K1: LayerNorm (fp64 accumulation) ----------------
__global__ __launch_bounds__(256) void k_ln(
    const float* __restrict__ gen, const float* __restrict__ cls,
    const float* __restrict__ box, const float* __restrict__ gamma,
    const float* __restrict__ beta, float* __restrict__ x,
    unsigned short* __restrict__ xbf) {
  int blk = blockIdx.x;
  int b = blk / Nn, n = blk % Nn;
  const float* src = (n == 0) ? cls + (size_t)b * Cc
                   : (n == 1) ? box + (size_t)b * Cc
                              : gen + ((size_t)b * NG + (n - 2)) * Cc;
  int t = threadIdx.x;
  float v0 = src[t], v1 = src[t + 256], v2 = src[t + 512];
  __shared__ double red[8];
  double s = (double)v0 + (double)v1 + (double)v2;
  for (int o = 32; o > 0; o >>= 1) s += __shfl_down(s, o, 64);
  int wid = t >> 6, lid = t & 63;
  if (lid == 0) red[wid] = s;
  __syncthreads();
  if (t == 0) red[4] = (red[0] + red[1] + red[2] + red[3]) / Cc;
  __syncthreads();
  double mean = red[4];
  double d0 = (double)v0 - mean, d1 = (double)v1 - mean, d2 = (double)v2 - mean;
  double sq = d0 * d0 + d1 * d1 + d2 * d2;
  for (int o = 32; o > 0; o >>= 1) sq += __shfl_down(sq, o, 64);
  __syncthreads();
  if (lid == 0) red[wid] = sq;
  __syncthreads();
  if (t == 0) {
    double var = (red[0] + red[1] + red[2] + red[3]) / Cc;
    red[5] = 1.0 / sqrt(var + 1e-5);
  }
  __syncthreads();
  double rs = red[5];
  float* dst = x + ((size_t)b * Nn + n) * Cc;
  unsigned short* dbf = xbf + ((size_t)b * NP + n) * Cc;
  float o0 = (float)(d0 * rs * (double)gamma[t]       + (double)beta[t]);
  float o1 = (float)(d1 * rs * (double)gamma[t + 256] + (double)beta[t + 256]);
  float o2 = (float)(d2 * rs * (double)gamma[t + 512] + (double)beta[t + 512]);
  dst[t] = o0; dst[t + 256] = o1; dst[t + 512] = o2;
  dbf[t] = f2bf(o0); dbf[t + 256] = f2bf(o1); dbf[t + 512] = f2bf(o2);
}

// ---------------- K1b: zero pad rows 1026..1087 of x_bf ----------------
__global__ __launch_bounds__(256) void k_padzero(unsigned short* __restrict__ xbf) {
  constexpr int PERB = (NP - Nn) * Cc / 2;  // uints per batch
  int idx = blockIdx.x * 256 + threadIdx.x;
  int total = Bn * PERB;
  for (int i = idx; i < total; i += gridDim.x * 256) {
    int b = i / PERB, r = i % PERB;
    unsigned int* p = (unsigned int*)(xbf + ((size_t)b * NP + Nn) * Cc);
    p[r] = 0u;
  }
}

// ---------------- K1c: transpose x_bf -> xT_bf [b][c][jpad] ----------------
__global__ __launch_bounds__(256) void k_xt(
    const unsigned short* __restrict__ xbf, unsigned short* __restrict__ xT) {
  int b = blockIdx.x, jt = blockIdx.y, ct = blockIdx.z;
  int j0 = jt * 64, c0 = ct * 64;
  __shared__ unsigned short ts[64][80];
  int t = threadIdx.x;
  #pragma unroll
  for (int l = 0; l < 2; l++) {
    int chunk = t + l * 256;
    int r = chunk >> 3, c8 = chunk & 7;
    uint4 v = *(const uint4*)(xbf + ((size_t)b * NP + j0 + r) * Cc + c0 + c8 * 8);
    *(uint4*)&ts[r][c8 * 8] = v;
  }
  __syncthreads();
  #pragma unroll
  for (int l = 0; l < 2; l++) {
    int chunk = t + l * 256;
    int orow = chunk >> 3, j8 = chunk & 7;
    unsigned short tmp[8];
    #pragma unroll
    for (int i = 0; i < 8; i++) tmp[i] = ts[j8 * 8 + i][orow];
    *(uint4*)(xT + ((size_t)b * Cc + c0 + orow) * NP + j0 + j8 * 8) = *(uint4*)tmp;
  }
}

// ---------------- K1d: convert Wv, Wproj to bf16 ----------------
__global__ __launch_bounds__(256) void k_wcvt(
    const float* __restrict__ wqkv, const float* __restrict__ wproj,
    unsigned short* __restrict__ wvb, unsigned short* __restrict__ wpb) {
  int i = (blockIdx.x * 256 + threadIdx.x) * 4;
  if (i >= Cc * Cc) return;
  const float* wv = wqkv + (size_t)2 * Cc * Cc;
  float4 a = *(const float4*)(wv + i);
  float4 b = *(const float4*)(wproj + i);
  ushort4 oa, ob;
  oa.x = f2bf(a.x); oa.y = f2bf(a.y); oa.z = f2bf(a.z); oa.w = f2bf(a.w);
  ob.x = f2bf(b.x); ob.y = f2bf(b.y); ob.z = f2bf(b.z); ob.w = f2bf(b.w);
  *(ushort4*)(wvb + i) = oa;
  *(ushort4*)(wpb + i) = ob;
}

// ---------------- K2: q rows 0,1 (fp64) ----------------
__global__ __launch_bounds__(256) void k_q01(
    const float* __restrict__ wqkv, const float* __restrict__ x,
    double* __restrict__ q01d) {
  int b = blockIdx.x >> 1, i = blockIdx.x & 1;
  __shared__ float xl[Cc];
  const float* xr = x + ((size_t)b * Nn + i) * Cc;
  for (int c = threadIdx.x; c < Cc; c += 256) xl[c] = xr[c];
  __syncthreads();
  for (int o = threadIdx.x; o < Cc; o += 256) {
    const float* wr = wqkv + (size_t)o * Cc;
    double a0 = 0, a1 = 0, a2 = 0, a3 = 0;
    for (int c = 0; c < Cc; c += 4) {
      a0 += (double)wr[c]     * (double)xl[c];
      a1 += (double)wr[c + 1] * (double)xl[c + 1];
      a2 += (double)wr[c + 2] * (double)xl[c + 2];
      a3 += (double)wr[c + 3] * (double)xl[c + 3];
    }
    q01d[((size_t)b * 2 + i) * Cc + o] = (a0 + a1) + (a2 + a3);
  }
}

// ---------------- K3: u rows 0,1 (fp64) ----------------
__global__ __launch_bounds__(256) void k_u01(
    const float* __restrict__ wqkv, const double* __restrict__ q01d,
    double* __restrict__ u01d) {
  int blk = blockIdx.x;
  int h = blk % Hh; int i = (blk / Hh) & 1; int b = blk / (2 * Hh);
  __shared__ double qh[HD];
  const double* q = q01d + ((size_t)b * 2 + i) * Cc + h * HD;
  for (int d = threadIdx.x; d < HD; d += 256) qh[d] = q[d];
  __syncthreads();
  const float* wk = wqkv + (size_t)Cc * Cc;
  for (int c = threadIdx.x; c < Cc; c += 256) {
    double acc = 0;
    for (int d = 0; d < HD; d++) acc += qh[d] * (double)wk[(size_t)(h * HD + d) * Cc + c];
    u01d[(((size_t)(b * 2 + i)) * Hh + h) * Cc + c] = acc;
  }
}

// ---------------- K4: routing logits rows 0,1 (fp64, K-split partials) -----
// grid (Bn, 5, 4): b, j-tile(256), c-chunk(192)
__global__ __launch_bounds__(256) void k_rlogits(
    const double* __restrict__ u01d, const float* __restrict__ x,
    double* __restrict__ Ldp) {
  int b = blockIdx.x, jt = blockIdx.y, cch = blockIdx.z;
  int j0 = jt * 256;
  int t = threadIdx.x;
  int pl = t & 127;
  int g  = t >> 7;
  __shared__ float xtT[32][256];
  __shared__ double ut[24][32];
  double acc[12][2] = {};
  int cbase = cch * 192;
  for (int c0 = cbase; c0 < cbase + 192; c0 += 32) {
    {
      int j = j0 + t;
      if (j < Nn) {
        const float* xr = x + ((size_t)b * Nn + j) * Cc + c0;
        #pragma unroll
        for (int k = 0; k < 32; k += 4) {
          float4 v = *(const float4*)(xr + k);
          xtT[k][t] = v.x; xtT[k + 1][t] = v.y; xtT[k + 2][t] = v.z; xtT[k + 3][t] = v.w;
        }
      } else {
        for (int k = 0; k < 32; k++) xtT[k][t] = 0.f;
      }
    }
    for (int idx = t; idx < 24 * 32; idx += 256) {
      int r = idx >> 5, cc = idx & 31;
      ut[r][cc] = u01d[(((size_t)(b * 2 + (r / 12))) * Hh + (r % 12)) * Cc + c0 + cc];
    }
    __syncthreads();
    for (int cc = 0; cc < 32; cc++) {
      float2 xv = *(const float2*)&xtT[cc][pl * 2];
      double x0 = (double)xv.x, x1 = (double)xv.y;
      #pragma unroll
      for (int h = 0; h < 12; h++) {
        double uv = ut[g * 12 + h][cc];
        acc[h][0] += uv * x0;
        acc[h][1] += uv * x1;
      }
    }
    __syncthreads();
  }
  for (int h = 0; h < 12; h++) {
    #pragma unroll
    for (int k = 0; k < 2; k++) {
      int j = j0 + pl * 2 + k;
      if (j < Nn) {
        Ldp[(((size_t)cch * Bn + b) * 24 + g * 12 + h) * Nn + j] = acc[h][k] * 0.125;
      }
    }
  }
}

// ---------------- K5: sum partials + mask + softmax (fp64) ----------------
__global__ __launch_bounds__(256) void k_rsoftmax(
    const double* __restrict__ Ldp, double* __restrict__ Ld,
    unsigned short* __restrict__ Pb) {
  int blk = blockIdx.x;
  int h = blk % Hh; int i = (blk / Hh) & 1; int b = blk / (2 * Hh);
  double* row = Ld + (size_t)blk * Nn;
  unsigned short* prow = Pb + ((size_t)b * 216 + i * Hh + h) * NP;
  int t = threadIdx.x;
  size_t poff = ((size_t)b * 24 + i * 12 + h) * Nn;
  constexpr size_t PSTRIDE = (size_t)Bn * 24 * Nn;
  double lv[5];
  int cnt = 0;
  double mx = -1e300;
  for (int j = t; j < Nn; j += 256) {
    double L = Ldp[poff + j] + Ldp[PSTRIDE + poff + j] +
               Ldp[2 * PSTRIDE + poff + j] + Ldp[3 * PSTRIDE + poff + j];
    if (i == 0 && j == 1) L = 0.0;
    if (i == 1 && j == 0) L = 0.0;
    lv[cnt++] = L;
    mx = fmax(mx, L);
  }
  __shared__ double sd[256];
  sd[t] = mx; __syncthreads();
  for (int st = 128; st > 0; st >>= 1) { if (t < st) sd[t] = fmax(sd[t], sd[t + st]); __syncthreads(); }
  mx = sd[0]; __syncthreads();
  double sum = 0;
  for (int k = 0; k < cnt; k++) { lv[k] = exp(lv[k] - mx); sum += lv[k]; }
  sd[t] = sum; __syncthreads();
  for (int st = 128; st > 0; st >>= 1) { if (t < st) sd[t] += sd[t + st]; __syncthreads(); }
  double inv = 1.0 / sd[0];
  int k = 0;
  for (int j = t; j < Nn; j += 256) {
    double p = lv[k++] * inv;
    row[j] = p;
    prow[j] = f2bf((float)p);
  }
  for (int j = Nn + t; j < NP; j += 256) prow[j] = 0;
}

// ---------------- K6: head means -> sum_a, diff (fp64) ----------------
__global__ __launch_bounds__(256) void k_rsums(
    const double* __restrict__ Ld, double* __restrict__ suma,
    double* __restrict__ diffd) {
  int b = blockIdx.x;
  for (int jg = threadIdx.x; jg < NG; jg += 256) {
    int j = jg + 2;
    double cs = 0, bs = 0;
    for (int h = 0; h < Hh; h++) {
      cs += Ld[(((size_t)(b * 2 + 0)) * Hh + h) * Nn + j];
      bs += Ld[(((size_t)(b * 2 + 1)) * Hh + h) * Nn + j];
    }
    cs /= 12.0; bs /= 12.0;
    suma[(size_t)b * NG + jg] = cs + bs;
    diffd[(size_t)b * NG + jg] = bs - cs;
  }
}

// ---------------- K7: routing ----------------
__global__ __launch_bounds__(256) void k_route(
    const double* __restrict__ suma, const double* __restrict__ diffd,
    int* __restrict__ rowcat) {
  int b = blockIdx.x, t = threadIdx.x;
  __shared__ double vals[NG];
  __shared__ unsigned char isbox[NG];
  __shared__ unsigned char picked[NG];
  __shared__ double rv[256];
  __shared__ int ri[256];
  __shared__ int blist[16], clist[16];
  for (int j = t; j < NG; j += 256) {
    vals[j] = suma[(size_t)b * NG + j];
    isbox[j] = diffd[(size_t)b * NG + j] > 0.0 ? 1 : 0;
    picked[j] = 0;
  }
  __syncthreads();
  for (int cat = 0; cat < 2; cat++) {
    for (int s = 0; s < 16; s++) {
      double bv = -1e300; int bi = -1;
      for (int j = t; j < NG; j += 256) {
        if (isbox[j] == cat && !picked[j]) {
          if (vals[j] > bv || (vals[j] == bv && j < bi)) { bv = vals[j]; bi = j; }
        }
      }
      rv[t] = bv; ri[t] = bi;
      __syncthreads();
      for (int st = 128; st > 0; st >>= 1) {
        if (t < st) {
          if (ri[t + st] >= 0 &&
              (ri[t] < 0 || rv[t + st] > rv[t] ||
               (rv[t + st] == rv[t] && ri[t + st] < ri[t]))) {
            rv[t] = rv[t + st]; ri[t] = ri[t + st];
          }
        }
        __syncthreads();
      }
      if (t == 0) {
        int w = ri[0];
        if (cat) blist[s] = w; else clist[s] = w;
        if (w >= 0) picked[w] = 1;
      }
      __syncthreads();
    }
  }
  if (t < 16) {
    int s = t;
    int bc = blist[s];
    int cl = clist[15 - s];
    int win;
    if (bc < 0 && cl < 0) win = -1;
    else if (bc < 0) win = cl;
    else if (cl < 0) win = bc;
    else {
      bool boxwins = (vals[bc] < vals[cl]) || (vals[bc] == vals[cl] && bc > cl);
      win = boxwins ? bc : cl;
    }
    int tok = (win >= 0) ? win : 0;
    rowcat[b * NR + 2 + s] = tok + 2;
  }
  if (t == 0) { rowcat[b * NR + 0] = 0; rowcat[b * NR + 1] = 1; }
}

// ---------------- K8: q for 16 gathered rows (fp32) ----------------
__global__ __launch_bounds__(256) void k_qg(
    const float* __restrict__ wqkv, const float* __restrict__ x,
    const int* __restrict__ rowcat, float* __restrict__ qf) {
  int b = blockIdx.x >> 4, s = blockIdx.x & 15;
  int tok = rowcat[b * NR + 2 + s];
  __shared__ float xl[Cc];
  const float* xr = x + ((size_t)b * Nn + tok) * Cc;
  for (int c = threadIdx.x; c < Cc; c += 256) xl[c] = xr[c];
  __syncthreads();
  for (int o = threadIdx.x; o < Cc; o += 256) {
    const float* wr = wqkv + (size_t)o * Cc;
    float a0 = 0, a1 = 0, a2 = 0, a3 = 0;
    for (int c = 0; c < Cc; c += 4) {
      a0 += wr[c] * xl[c]; a1 += wr[c + 1] * xl[c + 1];
      a2 += wr[c + 2] * xl[c + 2]; a3 += wr[c + 3] * xl[c + 3];
    }
    qf[((size_t)b * NR + 2 + s) * Cc + o] = (a0 + a1) + (a2 + a3);
  }
}

// ---------------- K9: u for gathered rows (fp32 compute, bf16 store) -------
__global__ __launch_bounds__(256) void k_ug(
    const float* __restrict__ wqkv, const float* __restrict__ qf,
    unsigned short* __restrict__ u16b) {
  int h = blockIdx.x, ct = blockIdx.y, bst = blockIdx.z;
  int t = threadIdx.x;
  int cq = t & 31, rg = t >> 5;
  int c0 = ct * 128;
  const float* wk = wqkv + (size_t)Cc * Cc + (size_t)h * HD * Cc;
  __shared__ float qt[64][17];
  __shared__ float wt[16][128];
  float acc[8][4] = {};
  for (int d0 = 0; d0 < HD; d0 += 16) {
    for (int idx = t; idx < 64 * 16; idx += 256) {
      int r = idx >> 4, dd = idx & 15;
      int bs = bst * 64 + r;
      int b = bs >> 4, s = bs & 15;
      qt[r][dd] = qf[((size_t)b * NR + 2 + s) * Cc + h * HD + d0 + dd];
    }
    for (int idx = t; idx < 16 * 128; idx += 256) {
      int dd = idx >> 7, cc = idx & 127;
      wt[dd][cc] = wk[(size_t)(d0 + dd) * Cc + c0 + cc];
    }
    __syncthreads();
    for (int dd = 0; dd < 16; dd++) {
      float4 wv = *(const float4*)&wt[dd][cq * 4];
      #pragma unroll
      for (int r = 0; r < 8; r++) {
        float qv = qt[rg * 8 + r][dd];
        acc[r][0] += qv * wv.x; acc[r][1] += qv * wv.y;
        acc[r][2] += qv * wv.z; acc[r][3] += qv * wv.w;
      }
    }
    __syncthreads();
  }
  for (int r = 0; r < 8; r++) {
    int bs = bst * 64 + rg * 8 + r;
    int b = bs >> 4, s = bs & 15;
    unsigned short* dst = u16b + ((size_t)b * 192 + s * Hh + h) * Cc + c0 + cq * 4;
    ushort4 o;
    o.x = f2bf(acc[r][0]); o.y = f2bf(acc[r][1]);
    o.z = f2bf(acc[r][2]); o.w = f2bf(acc[r][3]);
    *(ushort4*)dst = o;
  }
}

// ---------------- K10: gathered logits via MFMA ----------------
__global__ __launch_bounds__(256) void k_glogits_mfma(
    const unsigned short* __restrict__ u16b, const unsigned short* __restrict__ xbf,
    float* __restrict__ S) {
  int b = blockIdx.x, mg = blockIdx.y, nz = blockIdx.z;
  int wid = threadIdx.x >> 6, lane = threadIdx.x & 63;
  int mtile = mg * 4 + wid;
  int m = lane & 15, kg = lane >> 4;
  int row = mtile * 16 + m;
  const unsigned short* abase = u16b + ((size_t)b * 192 + row) * Cc + kg * 8;
  const unsigned short* bbase = xbf + (size_t)b * NP * Cc + kg * 8;
  f32x4 acc[5] = {{0,0,0,0},{0,0,0,0},{0,0,0,0},{0,0,0,0},{0,0,0,0}};
  int jb = nz * 80 + m;
  for (int k0 = 0; k0 < Cc; k0 += 32) {
    short8 a = *(const short8*)(abase + k0);
    #pragma unroll
    for (int t = 0; t < 5; t++) {
      short8 bf = *(const short8*)(bbase + (size_t)(jb + t * 16) * Cc + k0);
      acc[t] = __builtin_amdgcn_mfma_f32_16x16x32_bf16(a, bf, acc[t], 0, 0, 0);
    }
  }
  #pragma unroll
  for (int t = 0; t < 5; t++) {
    int col = nz * 80 + t * 16 + m;
    #pragma unroll
    for (int r = 0; r < 4; r++) {
      int rr = mtile * 16 + kg * 4 + r;
      S[((size_t)b * 192 + rr) * 1040 + col] = acc[t][r] * 0.125f;
    }
  }
}

// ---------------- K11: softmax for gathered rows (reads S, writes bf16 P) --
__global__ __launch_bounds__(256) void k_gsoftmax(
    const float* __restrict__ S, unsigned short* __restrict__ Pb) {
  int blk = blockIdx.x;
  int b = blk / 192, r = blk % 192;
  const float* row = S + ((size_t)b * 192 + r) * 1040;
  unsigned short* prow = Pb + ((size_t)b * 216 + 24 + r) * NP;
  int t = threadIdx.x;
  __shared__ float sd[256];
  float mx = -1e30f;
  for (int j = t; j < Nn; j += 256) mx = fmaxf(mx, row[j]);
  sd[t] = mx; __syncthreads();
  for (int st = 128; st > 0; st >>= 1) { if (t < st) sd[t] = fmaxf(sd[t], sd[t + st]); __syncthreads(); }
  mx = sd[0]; __syncthreads();
  float sum = 0;
  for (int j = t; j < Nn; j += 256) sum += __expf(row[j] - mx);
  sd[t] = sum; __syncthreads();
  for (int st = 128; st > 0; st >>= 1) { if (t < st) sd[t] += sd[t + st]; __syncthreads(); }
  float inv = 1.0f / sd[0];
  for (int j = t; j < NP; j += 256) {
    prow[j] = (j < Nn) ? f2bf(__expf(row[j] - mx) * inv) : (unsigned short)0;
  }
}

// ---------------- K12: wsum via MFMA (bf16 out) ----------------
__global__ __launch_bounds__(256) void k_wsum_mfma(
    const unsigned short* __restrict__ Pb, const unsigned short* __restrict__ xT,
    unsigned short* __restrict__ wsumb) {
  int b = blockIdx.x, mg = blockIdx.y, nz = blockIdx.z;
  int wid = threadIdx.x >> 6, lane = threadIdx.x & 63;
  int mtile = mg * 4 + wid;
  int m = lane & 15, kg = lane >> 4;
  int row = mtile * 16 + m;
  int rowc = row < 216 ? row : 215;
  const unsigned short* abase = Pb + ((size_t)b * 216 + rowc) * NP + kg * 8;
  const unsigned short* bbase = xT + (size_t)b * Cc * NP + kg * 8;
  f32x4 acc[6] = {{0,0,0,0},{0,0,0,0},{0,0,0,0},{0,0,0,0},{0,0,0,0},{0,0,0,0}};
  int cb = nz * 96 + m;
  for (int k0 = 0; k0 < NP; k0 += 32) {
    short8 a = *(const short8*)(abase + k0);
    #pragma unroll
    for (int t = 0; t < 6; t++) {
      short8 bf = *(const short8*)(bbase + (size_t)(cb + t * 16) * NP + k0);
      acc[t] = __builtin_amdgcn_mfma_f32_16x16x32_bf16(a, bf, acc[t], 0, 0, 0);
    }
  }
  #pragma unroll
  for (int t = 0; t < 6; t++) {
    int col = nz * 96 + t * 16 + m;
    #pragma unroll
    for (int r = 0; r < 4; r++) {
      int rr = mtile * 16 + kg * 4 + r;
      if (rr < 216) wsumb[((size_t)b * 216 + rr) * Cc + col] = f2bf(acc[t][r]);
    }
  }
}

// ---------------- K13: attnout = Wv * wsum via MFMA ----------------
// grid (Hh, 18): h, mtile of bi-rows. 4 waves = 4 d-tiles of 16.
__global__ __launch_bounds__(256) void k_attnout_mfma(
    const unsigned short* __restrict__ wsumb, const unsigned short* __restrict__ wvb,
    unsigned short* __restrict__ aob) {
  int h = blockIdx.x, mt = blockIdx.y;
  int wid = threadIdx.x >> 6, lane = threadIdx.x & 63;
  int m = lane & 15, kg = lane >> 4;
  int row = mt * 16 + m;                 // bi in [0,288)
  int b = row / NR, i = row % NR;
  const unsigned short* abase = wsumb + ((size_t)b * 216 + i * 12 + h) * Cc + kg * 8;
  const unsigned short* bbase = wvb + (size_t)(h * HD + wid * 16 + m) * Cc + kg * 8;
  f32x4 acc = {0, 0, 0, 0};
  for (int k0 = 0; k0 < Cc; k0 += 32) {
    short8 a = *(const short8*)(abase + k0);
    short8 bf = *(const short8*)(bbase + k0);
    acc = __builtin_amdgcn_mfma_f32_16x16x32_bf16(a, bf, acc, 0, 0, 0);
  }
  #pragma unroll
  for (int r = 0; r < 4; r++) {
    int orow = mt * 16 + kg * 4 + r;     // bi
    int ocol = h * HD + wid * 16 + m;    // channel
    aob[(size_t)orow * Cc + ocol] = f2bf(acc[r]);
  }
}

// ---------------- K14: proj via MFMA + bias + residual + scatter ----------
// grid (18, 12): mtile, ngroup. 4 waves = 4 n-tiles of 16.
__global__ __launch_bounds__(256) void k_proj_mfma(
    const unsigned short* __restrict__ aob, const unsigned short* __restrict__ wpb,
    const float* __restrict__ bproj, const int* __restrict__ rowcat,
    const float* __restrict__ gen, const float* __restrict__ cls,
    const float* __restrict__ box, float* __restrict__ out) {
  int mt = blockIdx.x, ng = blockIdx.y;
  int wid = threadIdx.x >> 6, lane = threadIdx.x & 63;
  int nt = ng * 4 + wid;                 // 0..47
  int m = lane & 15, kg = lane >> 4;
  const unsigned short* abase = aob + (size_t)(mt * 16 + m) * Cc + kg * 8;
  const unsigned short* bbase = wpb + (size_t)(nt * 16 + m) * Cc + kg * 8;
  f32x4 acc = {0, 0, 0, 0};
  for (int k0 = 0; k0 < Cc; k0 += 32) {
    short8 a = *(const short8*)(abase + k0);
    short8 bf = *(const short8*)(bbase + k0);
    acc = __builtin_amdgcn_mfma_f32_16x16x32_bf16(a, bf, acc, 0, 0, 0);
  }
  int c = nt * 16 + m;                   // output channel
  float bp = bproj[c];
  #pragma unroll
  for (int r = 0; r < 4; r++) {
    int bi = mt * 16 + kg * 4 + r;
    int b = bi / NR, i = bi % NR;
    int tok = rowcat[b * NR + i];
    const float* src = (tok == 0) ? cls + (size_t)b * Cc
                     : (tok == 1) ? box + (size_t)b * Cc
                                  : gen + ((size_t)b * NG + tok - 2) * Cc;
    float val = acc[r] + bp + src[c];
    float* dst;
    if (i == 0)       dst = out + ((size_t)b * 9 + 0) * Cc;
    else if (i == 1)  dst = out + (size_t)Bn * 9 * Cc + ((size_t)b * 9 + 0) * Cc;
    else if (i < 10)  dst = out + ((size_t)b * 9 + (i - 1)) * Cc;
    else              dst = out + (size_t)Bn * 9 * Cc + ((size_t)b * 9 + (i - 9)) * Cc;
    dst[c] = val;
  }
}

}  // namespace

extern "C" void kernel_launch(void* const* d_in, const int* in_sizes, int n_in,
                              void* d_out, int out_size, void* d_ws, size_t ws_size,
                              hipStream_t stream) {
  (void)in_sizes; (void)n_in; (void)out_size; (void)ws_size;
  const float* gen   = (const float*)d_in[0];
  const float* cls   = (const float*)d_in[1];
  const float* box   = (const float*)d_in[2];
  const float* wqkv  = (const float*)d_in[3];
  const float* wproj = (const float*)d_in[4];
  const float* bproj = (const float*)d_in[5];
  const float* gamma = (const float*)d_in[6];
  const float* beta  = (const float*)d_in[7];
  float* out = (float*)d_out;

  char* ws = (char*)d_ws;
  size_t off = 0;
  auto alloc = [&](size_t bytes) { void* p = ws + off; off += (bytes + 255) & ~(size_t)255; return p; };
  float* x             = (float*)alloc((size_t)Bn * Nn * Cc * 4);
  unsigned short* xbf  = (unsigned short*)alloc((size_t)Bn * NP * Cc * 2);
  unsigned short* xT   = (unsigned short*)alloc((size_t)Bn * Cc * NP * 2);
  float* qf            = (float*)alloc((size_t)Bn * NR * Cc * 4);
  unsigned short* u16b = (unsigned short*)alloc((size_t)Bn * 192 * Cc * 2);
  float* S             = (float*)alloc((size_t)Bn * 192 * 1040 * 4);
  unsigned short* Pb   = (unsigned short*)alloc((size_t)Bn * 216 * NP * 2);
  unsigned short* wsumb= (unsigned short*)alloc((size_t)Bn * 216 * Cc * 2);
  unsigned short* aob  = (unsigned short*)alloc((size_t)288 * Cc * 2);
  unsigned short* wvb  = (unsigned short*)alloc((size_t)Cc * Cc * 2);
  unsigned short* wpb  = (unsigned short*)alloc((size_t)Cc * Cc * 2);
  double* q01d         = (double*)alloc((size_t)Bn * 2 * Cc * 8);
  double* u01d         = (double*)alloc((size_t)Bn * 2 * Hh * Cc * 8);
  double* Ld           = (double*)alloc((size_t)Bn * 2 * Hh * Nn * 8);
  double* Ldp          = (double*)alloc((size_t)4 * Bn * 24 * Nn * 8);
  double* suma         = (double*)alloc((size_t)Bn * NG * 8);
  double* diffd        = (double*)alloc((size_t)Bn * NG * 8);
  int* rowcat          = (int*)alloc((size_t)Bn * NR * 4);

  k_ln<<<Bn * Nn, 256, 0, stream>>>(gen, cls, box, gamma, beta, x, xbf);
  k_padzero<<<48, 256, 0, stream>>>(xbf);
  k_xt<<<dim3(Bn, 17, 12), 256, 0, stream>>>(xbf, xT);
  k_wcvt<<<(Cc * Cc / 4 + 255) / 256, 256, 0, stream>>>(wqkv, wproj, wvb, wpb);
  k_q01<<<Bn * 2, 256, 0, stream>>>(wqkv, x, q01d);
  k_u01<<<Bn * 2 * Hh, 256, 0, stream>>>(wqkv, q01d, u01d);
  k_rlogits<<<dim3(Bn, 5, 4), 256, 0, stream>>>(u01d, x, Ldp);
  k_rsoftmax<<<Bn * 2 * Hh, 256, 0, stream>>>(Ldp, Ld, Pb);
  k_rsums<<<Bn, 256, 0, stream>>>(Ld, suma, diffd);
  k_route<<<Bn, 256, 0, stream>>>(suma, diffd, rowcat);
  k_qg<<<Bn * 16, 256, 0, stream>>>(wqkv, x, rowcat, qf);
  k_ug<<<dim3(Hh, 6, 4), 256, 0, stream>>>(wqkv, qf, u16b);
  k_glogits_mfma<<<dim3(Bn, 3, 13), 256, 0, stream>>>(u16b, xbf, S);
  k_gsoftmax<<<Bn * 192, 256, 0, stream>>>(S, Pb);
  k_wsum_mfma<<<dim3(Bn, 4, 8), 256, 0, stream>>>(Pb, xT, wsumb);
  k_attnout_mfma<<<dim3(Hh, 18), 256, 0, stream>>>(wsumb, wvb, aob);
  k_proj_mfma<<<dim3(18, 12), 256, 0, stream>>>(aob, wpb, bproj, rowcat, gen, cls, box, out);
}

// Round 4
// 447.840 us; speedup vs baseline: 2.5723x; 1.3558x over previous
//
#include <hip/hip_runtime.h>
#include <math.h>

namespace {

constexpr int Bn = 16;    // batch
constexpr int NG = 1024;  // general tokens
constexpr int Cc = 768;   // channels
constexpr int Hh = 12;    // heads
constexpr int HD = 64;    // head dim
constexpr int Nn = 1026;  // total tokens (cls, box, general)
constexpr int NR = 18;    // rows we actually need: 0,1 + 16 routed
constexpr int NP = 1088;  // padded token count (17*64) for MFMA K / N
constexpr int NCH = 8;    // K-chunks for k_rlogits

typedef __attribute__((ext_vector_type(8))) short short8;
typedef __attribute__((ext_vector_type(4))) float f32x4;

__device__ inline unsigned short f2bf(float f) {
  unsigned u = __float_as_uint(f);
  unsigned r = u + 0x7FFFu + ((u >> 16) & 1u);
  return (unsigned short)(r >> 16);
}

// ---------------- K1: LayerNorm (fp64 accumulation) ----------------
__global__ __launch_bounds__(256) void k_ln(
    const float* __restrict__ gen, const float* __restrict__ cls,
    const float* __restrict__ box, const float* __restrict__ gamma,
    const float* __restrict__ beta, float* __restrict__ x,
    unsigned short* __restrict__ xbf) {
  int blk = blockIdx.x;
  int b = blk / Nn, n = blk % Nn;
  const float* src = (n == 0) ? cls + (size_t)b * Cc
                   : (n == 1) ? box + (size_t)b * Cc
                              : gen + ((size_t)b * NG + (n - 2)) * Cc;
  int t = threadIdx.x;
  float v0 = src[t], v1 = src[t + 256], v2 = src[t + 512];
  __shared__ double red[8];
  double s = (double)v0 + (double)v1 + (double)v2;
  for (int o = 32; o > 0; o >>= 1) s += __shfl_down(s, o, 64);
  int wid = t >> 6, lid = t & 63;
  if (lid == 0) red[wid] = s;
  __syncthreads();
  if (t == 0) red[4] = (red[0] + red[1] + red[2] + red[3]) / Cc;
  __syncthreads();
  double mean = red[4];
  double d0 = (double)v0 - mean, d1 = (double)v1 - mean, d2 = (double)v2 - mean;
  double sq = d0 * d0 + d1 * d1 + d2 * d2;
  for (int o = 32; o > 0; o >>= 1) sq += __shfl_down(sq, o, 64);
  __syncthreads();
  if (lid == 0) red[wid] = sq;
  __syncthreads();
  if (t == 0) {
    double var = (red[0] + red[1] + red[2] + red[3]) / Cc;
    red[5] = 1.0 / sqrt(var + 1e-5);
  }
  __syncthreads();
  double rs = red[5];
  float* dst = x + ((size_t)b * Nn + n) * Cc;
  unsigned short* dbf = xbf + ((size_t)b * NP + n) * Cc;
  float o0 = (float)(d0 * rs * (double)gamma[t]       + (double)beta[t]);
  float o1 = (float)(d1 * rs * (double)gamma[t + 256] + (double)beta[t + 256]);
  float o2 = (float)(d2 * rs * (double)gamma[t + 512] + (double)beta[t + 512]);
  dst[t] = o0; dst[t + 256] = o1; dst[t + 512] = o2;
  dbf[t] = f2bf(o0); dbf[t + 256] = f2bf(o1); dbf[t + 512] = f2bf(o2);
}

// ---------------- K1b: zero pad rows 1026..1087 of x_bf ----------------
__global__ __launch_bounds__(256) void k_padzero(unsigned short* __restrict__ xbf) {
  constexpr int PERB = (NP - Nn) * Cc / 2;  // uints per batch
  int idx = blockIdx.x * 256 + threadIdx.x;
  int total = Bn * PERB;
  for (int i = idx; i < total; i += gridDim.x * 256) {
    int b = i / PERB, r = i % PERB;
    unsigned int* p = (unsigned int*)(xbf + ((size_t)b * NP + Nn) * Cc);
    p[r] = 0u;
  }
}

// ---------------- K1c: transpose x_bf -> xT_bf [b][c][jpad] ----------------
__global__ __launch_bounds__(256) void k_xt(
    const unsigned short* __restrict__ xbf, unsigned short* __restrict__ xT) {
  int b = blockIdx.x, jt = blockIdx.y, ct = blockIdx.z;
  int j0 = jt * 64, c0 = ct * 64;
  __shared__ unsigned short ts[64][80];
  int t = threadIdx.x;
  #pragma unroll
  for (int l = 0; l < 2; l++) {
    int chunk = t + l * 256;
    int r = chunk >> 3, c8 = chunk & 7;
    uint4 v = *(const uint4*)(xbf + ((size_t)b * NP + j0 + r) * Cc + c0 + c8 * 8);
    *(uint4*)&ts[r][c8 * 8] = v;
  }
  __syncthreads();
  #pragma unroll
  for (int l = 0; l < 2; l++) {
    int chunk = t + l * 256;
    int orow = chunk >> 3, j8 = chunk & 7;
    unsigned short tmp[8];
    #pragma unroll
    for (int i = 0; i < 8; i++) tmp[i] = ts[j8 * 8 + i][orow];
    *(uint4*)(xT + ((size_t)b * Cc + c0 + orow) * NP + j0 + j8 * 8) = *(uint4*)tmp;
  }
}

// ---------------- K1d: convert Wv, Wproj to bf16 ----------------
__global__ __launch_bounds__(256) void k_wcvt(
    const float* __restrict__ wqkv, const float* __restrict__ wproj,
    unsigned short* __restrict__ wvb, unsigned short* __restrict__ wpb) {
  int i = (blockIdx.x * 256 + threadIdx.x) * 4;
  if (i >= Cc * Cc) return;
  const float* wv = wqkv + (size_t)2 * Cc * Cc;
  float4 a = *(const float4*)(wv + i);
  float4 b = *(const float4*)(wproj + i);
  ushort4 oa, ob;
  oa.x = f2bf(a.x); oa.y = f2bf(a.y); oa.z = f2bf(a.z); oa.w = f2bf(a.w);
  ob.x = f2bf(b.x); ob.y = f2bf(b.y); ob.z = f2bf(b.z); ob.w = f2bf(b.w);
  *(ushort4*)(wvb + i) = oa;
  *(ushort4*)(wpb + i) = ob;
}

// ---------------- K2: q rows 0,1 (fp64) — one wave per output ----------------
// grid (32, 192): row (b*2+i), o-tile of 4. wave w -> output o = ot*4+w.
__global__ __launch_bounds__(256) void k_q01(
    const float* __restrict__ wqkv, const float* __restrict__ x,
    double* __restrict__ q01d) {
  int row = blockIdx.x;
  int b = row >> 1, i = row & 1;
  __shared__ float xl[Cc];
  const float* xr = x + ((size_t)b * Nn + i) * Cc;
  for (int c = threadIdx.x; c < Cc; c += 256) xl[c] = xr[c];
  __syncthreads();
  int w = threadIdx.x >> 6, lane = threadIdx.x & 63;
  int o = blockIdx.y * 4 + w;
  const float* wr = wqkv + (size_t)o * Cc + lane * 12;
  const float* xs = xl + lane * 12;
  double acc = 0;
  #pragma unroll
  for (int k = 0; k < 12; k++) acc += (double)wr[k] * (double)xs[k];
  for (int off = 32; off > 0; off >>= 1) acc += __shfl_down(acc, off, 64);
  if (lane == 0) q01d[(size_t)row * Cc + o] = acc;
}

// ---------------- K3: u rows 0,1 (fp64), c-split ----------------
// grid (Bn*2*Hh, 3)
__global__ __launch_bounds__(256) void k_u01(
    const float* __restrict__ wqkv, const double* __restrict__ q01d,
    double* __restrict__ u01d) {
  int blk = blockIdx.x;
  int h = blk % Hh; int i = (blk / Hh) & 1; int b = blk / (2 * Hh);
  __shared__ double qh[HD];
  const double* q = q01d + ((size_t)b * 2 + i) * Cc + h * HD;
  if (threadIdx.x < HD) qh[threadIdx.x] = q[threadIdx.x];
  __syncthreads();
  const float* wk = wqkv + (size_t)Cc * Cc;
  int c = blockIdx.y * 256 + threadIdx.x;
  double a0 = 0, a1 = 0, a2 = 0, a3 = 0;
  #pragma unroll 4
  for (int d = 0; d < HD; d += 4) {
    a0 += qh[d]     * (double)wk[(size_t)(h * HD + d) * Cc + c];
    a1 += qh[d + 1] * (double)wk[(size_t)(h * HD + d + 1) * Cc + c];
    a2 += qh[d + 2] * (double)wk[(size_t)(h * HD + d + 2) * Cc + c];
    a3 += qh[d + 3] * (double)wk[(size_t)(h * HD + d + 3) * Cc + c];
  }
  u01d[(((size_t)(b * 2 + i)) * Hh + h) * Cc + c] = (a0 + a1) + (a2 + a3);
}

// ---------------- K4: routing logits rows 0,1 (fp64, 8 K-chunks) -----------
// grid (Bn, 5, NCH): b, j-tile(256), c-chunk(96)
__global__ __launch_bounds__(256) void k_rlogits(
    const double* __restrict__ u01d, const float* __restrict__ x,
    double* __restrict__ Ldp) {
  int b = blockIdx.x, jt = blockIdx.y, cch = blockIdx.z;
  int j0 = jt * 256;
  int t = threadIdx.x;
  int pl = t & 127;
  int g  = t >> 7;
  __shared__ float xtT[32][256];
  __shared__ double ut[24][32];
  double acc[12][2] = {};
  int cbase = cch * 96;
  for (int c0 = cbase; c0 < cbase + 96; c0 += 32) {
    {
      int j = j0 + t;
      if (j < Nn) {
        const float* xr = x + ((size_t)b * Nn + j) * Cc + c0;
        #pragma unroll
        for (int k = 0; k < 32; k += 4) {
          float4 v = *(const float4*)(xr + k);
          xtT[k][t] = v.x; xtT[k + 1][t] = v.y; xtT[k + 2][t] = v.z; xtT[k + 3][t] = v.w;
        }
      } else {
        for (int k = 0; k < 32; k++) xtT[k][t] = 0.f;
      }
    }
    for (int idx = t; idx < 24 * 32; idx += 256) {
      int r = idx >> 5, cc = idx & 31;
      ut[r][cc] = u01d[(((size_t)(b * 2 + (r / 12))) * Hh + (r % 12)) * Cc + c0 + cc];
    }
    __syncthreads();
    for (int cc = 0; cc < 32; cc++) {
      float2 xv = *(const float2*)&xtT[cc][pl * 2];
      double x0 = (double)xv.x, x1 = (double)xv.y;
      #pragma unroll
      for (int h = 0; h < 12; h++) {
        double uv = ut[g * 12 + h][cc];
        acc[h][0] += uv * x0;
        acc[h][1] += uv * x1;
      }
    }
    __syncthreads();
  }
  for (int h = 0; h < 12; h++) {
    #pragma unroll
    for (int k = 0; k < 2; k++) {
      int j = j0 + pl * 2 + k;
      if (j < Nn) {
        Ldp[(((size_t)cch * Bn + b) * 24 + g * 12 + h) * Nn + j] = acc[h][k] * 0.125;
      }
    }
  }
}

// ---------------- K5: sum partials + mask + softmax (fp64) ----------------
__global__ __launch_bounds__(256) void k_rsoftmax(
    const double* __restrict__ Ldp, double* __restrict__ Ld,
    unsigned short* __restrict__ Pb) {
  int blk = blockIdx.x;
  int h = blk % Hh; int i = (blk / Hh) & 1; int b = blk / (2 * Hh);
  double* row = Ld + (size_t)blk * Nn;
  unsigned short* prow = Pb + ((size_t)b * 216 + i * Hh + h) * NP;
  int t = threadIdx.x;
  size_t poff = ((size_t)b * 24 + i * 12 + h) * Nn;
  constexpr size_t PSTRIDE = (size_t)Bn * 24 * Nn;
  double lv[5];
  int cnt = 0;
  double mx = -1e300;
  for (int j = t; j < Nn; j += 256) {
    double L = 0;
    #pragma unroll
    for (int p = 0; p < NCH; p++) L += Ldp[(size_t)p * PSTRIDE + poff + j];
    if (i == 0 && j == 1) L = 0.0;
    if (i == 1 && j == 0) L = 0.0;
    lv[cnt++] = L;
    mx = fmax(mx, L);
  }
  __shared__ double sd[256];
  sd[t] = mx; __syncthreads();
  for (int st = 128; st > 0; st >>= 1) { if (t < st) sd[t] = fmax(sd[t], sd[t + st]); __syncthreads(); }
  mx = sd[0]; __syncthreads();
  double sum = 0;
  for (int k = 0; k < cnt; k++) { lv[k] = exp(lv[k] - mx); sum += lv[k]; }
  sd[t] = sum; __syncthreads();
  for (int st = 128; st > 0; st >>= 1) { if (t < st) sd[t] += sd[t + st]; __syncthreads(); }
  double inv = 1.0 / sd[0];
  int k = 0;
  for (int j = t; j < Nn; j += 256) {
    double p = lv[k++] * inv;
    row[j] = p;
    prow[j] = f2bf((float)p);
  }
  for (int j = Nn + t; j < NP; j += 256) prow[j] = 0;
}

// ---------------- K6: head means -> sum_a, diff (fp64) ----------------
__global__ __launch_bounds__(256) void k_rsums(
    const double* __restrict__ Ld, double* __restrict__ suma,
    double* __restrict__ diffd) {
  int b = blockIdx.x;
  for (int jg = threadIdx.x; jg < NG; jg += 256) {
    int j = jg + 2;
    double cs = 0, bs = 0;
    for (int h = 0; h < Hh; h++) {
      cs += Ld[(((size_t)(b * 2 + 0)) * Hh + h) * Nn + j];
      bs += Ld[(((size_t)(b * 2 + 1)) * Hh + h) * Nn + j];
    }
    cs /= 12.0; bs /= 12.0;
    suma[(size_t)b * NG + jg] = cs + bs;
    diffd[(size_t)b * NG + jg] = bs - cs;
  }
}

// ---------------- K7: routing — both cats concurrent, shuffle argmax -------
// grid (Bn). waves 0,1 = cls (cat0), waves 2,3 = box (cat1).
__global__ __launch_bounds__(256) void k_route(
    const double* __restrict__ suma, const double* __restrict__ diffd,
    int* __restrict__ rowcat) {
  int b = blockIdx.x, t = threadIdx.x;
  __shared__ double vals[NG];
  __shared__ unsigned char flags[NG];
  __shared__ double redv[4];
  __shared__ int redi[4];
  __shared__ int blist[16], clist[16];
  __shared__ double blv[16], clv[16];
  for (int j = t; j < NG; j += 256) {
    vals[j] = suma[(size_t)b * NG + j];
    flags[j] = diffd[(size_t)b * NG + j] > 0.0 ? 1 : 0;
  }
  __syncthreads();
  int half = t >> 7;        // category this thread serves
  int lt = t & 127;
  int wv = t >> 6;          // wave id 0..3
  int lane = t & 63;
  for (int s = 0; s < 16; s++) {
    double bv = -1e300; int bi = 0x7fffffff;
    #pragma unroll
    for (int k = 0; k < 8; k++) {
      int j = lt * 8 + k;
      double v = vals[j];
      if (flags[j] == half && v > bv) { bv = v; bi = j; }
    }
    for (int off = 32; off > 0; off >>= 1) {
      double ov = __shfl_down(bv, off, 64);
      int oi = __shfl_down(bi, off, 64);
      if (ov > bv || (ov == bv && oi < bi)) { bv = ov; bi = oi; }
    }
    if (lane == 0) { redv[wv] = bv; redi[wv] = bi; }
    __syncthreads();
    if (lt == 0) {
      double v0 = redv[half * 2], v1 = redv[half * 2 + 1];
      int i0 = redi[half * 2], i1 = redi[half * 2 + 1];
      if (v1 > v0 || (v1 == v0 && i1 < i0)) { v0 = v1; i0 = i1; }
      int win = (v0 > -1e299) ? i0 : -1;
      if (half) { blist[s] = win; blv[s] = v0; }
      else      { clist[s] = win; clv[s] = v0; }
      if (win >= 0) vals[win] = -1e300;   // mark picked (value saved above)
    }
    __syncthreads();
  }
  if (t < 16) {
    int s = t;
    int bc = blist[s];
    int cl = clist[15 - s];
    double bvv = blv[s], cvv = clv[15 - s];
    int win;
    if (bc < 0 && cl < 0) win = -1;
    else if (bc < 0) win = cl;
    else if (cl < 0) win = bc;
    else {
      bool boxwins = (bvv < cvv) || (bvv == cvv && bc > cl);
      win = boxwins ? bc : cl;
    }
    int tok = (win >= 0) ? win : 0;
    rowcat[b * NR + 2 + s] = tok + 2;
  }
  if (t == 0) { rowcat[b * NR + 0] = 0; rowcat[b * NR + 1] = 1; }
}

// ---------------- K8: q for 16 gathered rows (fp32) ----------------
__global__ __launch_bounds__(256) void k_qg(
    const float* __restrict__ wqkv, const float* __restrict__ x,
    const int* __restrict__ rowcat, float* __restrict__ qf) {
  int b = blockIdx.x >> 4, s = blockIdx.x & 15;
  int tok = rowcat[b * NR + 2 + s];
  __shared__ float xl[Cc];
  const float* xr = x + ((size_t)b * Nn + tok) * Cc;
  for (int c = threadIdx.x; c < Cc; c += 256) xl[c] = xr[c];
  __syncthreads();
  for (int o = threadIdx.x; o < Cc; o += 256) {
    const float* wr = wqkv + (size_t)o * Cc;
    float a0 = 0, a1 = 0, a2 = 0, a3 = 0;
    for (int c = 0; c < Cc; c += 4) {
      a0 += wr[c] * xl[c]; a1 += wr[c + 1] * xl[c + 1];
      a2 += wr[c + 2] * xl[c + 2]; a3 += wr[c + 3] * xl[c + 3];
    }
    qf[((size_t)b * NR + 2 + s) * Cc + o] = (a0 + a1) + (a2 + a3);
  }
}

// ---------------- K9: u for gathered rows (fp32 compute, bf16 store) -------
__global__ __launch_bounds__(256) void k_ug(
    const float* __restrict__ wqkv, const float* __restrict__ qf,
    unsigned short* __restrict__ u16b) {
  int h = blockIdx.x, ct = blockIdx.y, bst = blockIdx.z;
  int t = threadIdx.x;
  int cq = t & 31, rg = t >> 5;
  int c0 = ct * 128;
  const float* wk = wqkv + (size_t)Cc * Cc + (size_t)h * HD * Cc;
  __shared__ float qt[64][17];
  __shared__ float wt[16][128];
  float acc[8][4] = {};
  for (int d0 = 0; d0 < HD; d0 += 16) {
    for (int idx = t; idx < 64 * 16; idx += 256) {
      int r = idx >> 4, dd = idx & 15;
      int bs = bst * 64 + r;
      int b = bs >> 4, s = bs & 15;
      qt[r][dd] = qf[((size_t)b * NR + 2 + s) * Cc + h * HD + d0 + dd];
    }
    for (int idx = t; idx < 16 * 128; idx += 256) {
      int dd = idx >> 7, cc = idx & 127;
      wt[dd][cc] = wk[(size_t)(d0 + dd) * Cc + c0 + cc];
    }
    __syncthreads();
    for (int dd = 0; dd < 16; dd++) {
      float4 wv = *(const float4*)&wt[dd][cq * 4];
      #pragma unroll
      for (int r = 0; r < 8; r++) {
        float qv = qt[rg * 8 + r][dd];
        acc[r][0] += qv * wv.x; acc[r][1] += qv * wv.y;
        acc[r][2] += qv * wv.z; acc[r][3] += qv * wv.w;
      }
    }
    __syncthreads();
  }
  for (int r = 0; r < 8; r++) {
    int bs = bst * 64 + rg * 8 + r;
    int b = bs >> 4, s = bs & 15;
    unsigned short* dst = u16b + ((size_t)b * 192 + s * Hh + h) * Cc + c0 + cq * 4;
    ushort4 o;
    o.x = f2bf(acc[r][0]); o.y = f2bf(acc[r][1]);
    o.z = f2bf(acc[r][2]); o.w = f2bf(acc[r][3]);
    *(ushort4*)dst = o;
  }
}

// ---------------- K10: gathered logits via MFMA ----------------
__global__ __launch_bounds__(256) void k_glogits_mfma(
    const unsigned short* __restrict__ u16b, const unsigned short* __restrict__ xbf,
    float* __restrict__ S) {
  int b = blockIdx.x, mg = blockIdx.y, nz = blockIdx.z;
  int wid = threadIdx.x >> 6, lane = threadIdx.x & 63;
  int mtile = mg * 4 + wid;
  int m = lane & 15, kg = lane >> 4;
  int row = mtile * 16 + m;
  const unsigned short* abase = u16b + ((size_t)b * 192 + row) * Cc + kg * 8;
  const unsigned short* bbase = xbf + (size_t)b * NP * Cc + kg * 8;
  f32x4 acc[5] = {{0,0,0,0},{0,0,0,0},{0,0,0,0},{0,0,0,0},{0,0,0,0}};
  int jb = nz * 80 + m;
  for (int k0 = 0; k0 < Cc; k0 += 32) {
    short8 a = *(const short8*)(abase + k0);
    #pragma unroll
    for (int t = 0; t < 5; t++) {
      short8 bf = *(const short8*)(bbase + (size_t)(jb + t * 16) * Cc + k0);
      acc[t] = __builtin_amdgcn_mfma_f32_16x16x32_bf16(a, bf, acc[t], 0, 0, 0);
    }
  }
  #pragma unroll
  for (int t = 0; t < 5; t++) {
    int col = nz * 80 + t * 16 + m;
    #pragma unroll
    for (int r = 0; r < 4; r++) {
      int rr = mtile * 16 + kg * 4 + r;
      S[((size_t)b * 192 + rr) * 1040 + col] = acc[t][r] * 0.125f;
    }
  }
}

// ---------------- K11: softmax for gathered rows (reads S, writes bf16 P) --
__global__ __launch_bounds__(256) void k_gsoftmax(
    const float* __restrict__ S, unsigned short* __restrict__ Pb) {
  int blk = blockIdx.x;
  int b = blk / 192, r = blk % 192;
  const float* row = S + ((size_t)b * 192 + r) * 1040;
  unsigned short* prow = Pb + ((size_t)b * 216 + 24 + r) * NP;
  int t = threadIdx.x;
  __shared__ float sd[256];
  float mx = -1e30f;
  for (int j = t; j < Nn; j += 256) mx = fmaxf(mx, row[j]);
  sd[t] = mx; __syncthreads();
  for (int st = 128; st > 0; st >>= 1) { if (t < st) sd[t] = fmaxf(sd[t], sd[t + st]); __syncthreads(); }
  mx = sd[0]; __syncthreads();
  float sum = 0;
  for (int j = t; j < Nn; j += 256) sum += __expf(row[j] - mx);
  sd[t] = sum; __syncthreads();
  for (int st = 128; st > 0; st >>= 1) { if (t < st) sd[t] += sd[t + st]; __syncthreads(); }
  float inv = 1.0f / sd[0];
  for (int j = t; j < NP; j += 256) {
    prow[j] = (j < Nn) ? f2bf(__expf(row[j] - mx) * inv) : (unsigned short)0;
  }
}

// ---------------- K12: wsum via MFMA (bf16 out) ----------------
__global__ __launch_bounds__(256) void k_wsum_mfma(
    const unsigned short* __restrict__ Pb, const unsigned short* __restrict__ xT,
    unsigned short* __restrict__ wsumb) {
  int b = blockIdx.x, mg = blockIdx.y, nz = blockIdx.z;
  int wid = threadIdx.x >> 6, lane = threadIdx.x & 63;
  int mtile = mg * 4 + wid;
  int m = lane & 15, kg = lane >> 4;
  int row = mtile * 16 + m;
  int rowc = row < 216 ? row : 215;
  const unsigned short* abase = Pb + ((size_t)b * 216 + rowc) * NP + kg * 8;
  const unsigned short* bbase = xT + (size_t)b * Cc * NP + kg * 8;
  f32x4 acc[6] = {{0,0,0,0},{0,0,0,0},{0,0,0,0},{0,0,0,0},{0,0,0,0},{0,0,0,0}};
  int cb = nz * 96 + m;
  for (int k0 = 0; k0 < NP; k0 += 32) {
    short8 a = *(const short8*)(abase + k0);
    #pragma unroll
    for (int t = 0; t < 6; t++) {
      short8 bf = *(const short8*)(bbase + (size_t)(cb + t * 16) * NP + k0);
      acc[t] = __builtin_amdgcn_mfma_f32_16x16x32_bf16(a, bf, acc[t], 0, 0, 0);
    }
  }
  #pragma unroll
  for (int t = 0; t < 6; t++) {
    int col = nz * 96 + t * 16 + m;
    #pragma unroll
    for (int r = 0; r < 4; r++) {
      int rr = mtile * 16 + kg * 4 + r;
      if (rr < 216) wsumb[((size_t)b * 216 + rr) * Cc + col] = f2bf(acc[t][r]);
    }
  }
}

// ---------------- K13: attnout = Wv * wsum via MFMA ----------------
__global__ __launch_bounds__(256) void k_attnout_mfma(
    const unsigned short* __restrict__ wsumb, const unsigned short* __restrict__ wvb,
    unsigned short* __restrict__ aob) {
  int h = blockIdx.x, mt = blockIdx.y;
  int wid = threadIdx.x >> 6, lane = threadIdx.x & 63;
  int m = lane & 15, kg = lane >> 4;
  int row = mt * 16 + m;                 // bi in [0,288)
  int b = row / NR, i = row % NR;
  const unsigned short* abase = wsumb + ((size_t)b * 216 + i * 12 + h) * Cc + kg * 8;
  const unsigned short* bbase = wvb + (size_t)(h * HD + wid * 16 + m) * Cc + kg * 8;
  f32x4 acc = {0, 0, 0, 0};
  for (int k0 = 0; k0 < Cc; k0 += 32) {
    short8 a = *(const short8*)(abase + k0);
    short8 bf = *(const short8*)(bbase + k0);
    acc = __builtin_amdgcn_mfma_f32_16x16x32_bf16(a, bf, acc, 0, 0, 0);
  }
  #pragma unroll
  for (int r = 0; r < 4; r++) {
    int orow = mt * 16 + kg * 4 + r;
    int ocol = h * HD + wid * 16 + m;
    aob[(size_t)orow * Cc + ocol] = f2bf(acc[r]);
  }
}

// ---------------- K14: proj via MFMA + bias + residual + scatter ----------
__global__ __launch_bounds__(256) void k_proj_mfma(
    const unsigned short* __restrict__ aob, const unsigned short* __restrict__ wpb,
    const float* __restrict__ bproj, const int* __restrict__ rowcat,
    const float* __restrict__ gen, const float* __restrict__ cls,
    const float* __restrict__ box, float* __restrict__ out) {
  int mt = blockIdx.x, ng = blockIdx.y;
  int wid = threadIdx.x >> 6, lane = threadIdx.x & 63;
  int nt = ng * 4 + wid;
  int m = lane & 15, kg = lane >> 4;
  const unsigned short* abase = aob + (size_t)(mt * 16 + m) * Cc + kg * 8;
  const unsigned short* bbase = wpb + (size_t)(nt * 16 + m) * Cc + kg * 8;
  f32x4 acc = {0, 0, 0, 0};
  for (int k0 = 0; k0 < Cc; k0 += 32) {
    short8 a = *(const short8*)(abase + k0);
    short8 bf = *(const short8*)(bbase + k0);
    acc = __builtin_amdgcn_mfma_f32_16x16x32_bf16(a, bf, acc, 0, 0, 0);
  }
  int c = nt * 16 + m;
  float bp = bproj[c];
  #pragma unroll
  for (int r = 0; r < 4; r++) {
    int bi = mt * 16 + kg * 4 + r;
    int b = bi / NR, i = bi % NR;
    int tok = rowcat[b * NR + i];
    const float* src = (tok == 0) ? cls + (size_t)b * Cc
                     : (tok == 1) ? box + (size_t)b * Cc
                                  : gen + ((size_t)b * NG + tok - 2) * Cc;
    float val = acc[r] + bp + src[c];
    float* dst;
    if (i == 0)       dst = out + ((size_t)b * 9 + 0) * Cc;
    else if (i == 1)  dst = out + (size_t)Bn * 9 * Cc + ((size_t)b * 9 + 0) * Cc;
    else if (i < 10)  dst = out + ((size_t)b * 9 + (i - 1)) * Cc;
    else              dst = out + (size_t)Bn * 9 * Cc + ((size_t)b * 9 + (i - 9)) * Cc;
    dst[c] = val;
  }
}

}  // namespace

extern "C" void kernel_launch(void* const* d_in, const int* in_sizes, int n_in,
                              void* d_out, int out_size, void* d_ws, size_t ws_size,
                              hipStream_t stream) {
  (void)in_sizes; (void)n_in; (void)out_size; (void)ws_size;
  const float* gen   = (const float*)d_in[0];
  const float* cls   = (const float*)d_in[1];
  const float* box   = (const float*)d_in[2];
  const float* wqkv  = (const float*)d_in[3];
  const float* wproj = (const float*)d_in[4];
  const float* bproj = (const float*)d_in[5];
  const float* gamma = (const float*)d_in[6];
  const float* beta  = (const float*)d_in[7];
  float* out = (float*)d_out;

  char* ws = (char*)d_ws;
  size_t off = 0;
  auto alloc = [&](size_t bytes) { void* p = ws + off; off += (bytes + 255) & ~(size_t)255; return p; };
  float* x             = (float*)alloc((size_t)Bn * Nn * Cc * 4);
  unsigned short* xbf  = (unsigned short*)alloc((size_t)Bn * NP * Cc * 2);
  unsigned short* xT   = (unsigned short*)alloc((size_t)Bn * Cc * NP * 2);
  float* qf            = (float*)alloc((size_t)Bn * NR * Cc * 4);
  unsigned short* u16b = (unsigned short*)alloc((size_t)Bn * 192 * Cc * 2);
  float* S             = (float*)alloc((size_t)Bn * 192 * 1040 * 4);
  unsigned short* Pb   = (unsigned short*)alloc((size_t)Bn * 216 * NP * 2);
  unsigned short* wsumb= (unsigned short*)alloc((size_t)Bn * 216 * Cc * 2);
  unsigned short* aob  = (unsigned short*)alloc((size_t)288 * Cc * 2);
  unsigned short* wvb  = (unsigned short*)alloc((size_t)Cc * Cc * 2);
  unsigned short* wpb  = (unsigned short*)alloc((size_t)Cc * Cc * 2);
  double* q01d         = (double*)alloc((size_t)Bn * 2 * Cc * 8);
  double* u01d         = (double*)alloc((size_t)Bn * 2 * Hh * Cc * 8);
  double* Ld           = (double*)alloc((size_t)Bn * 2 * Hh * Nn * 8);
  double* Ldp          = (double*)alloc((size_t)NCH * Bn * 24 * Nn * 8);
  double* suma         = (double*)alloc((size_t)Bn * NG * 8);
  double* diffd        = (double*)alloc((size_t)Bn * NG * 8);
  int* rowcat          = (int*)alloc((size_t)Bn * NR * 4);

  k_ln<<<Bn * Nn, 256, 0, stream>>>(gen, cls, box, gamma, beta, x, xbf);
  k_padzero<<<48, 256, 0, stream>>>(xbf);
  k_xt<<<dim3(Bn, 17, 12), 256, 0, stream>>>(xbf, xT);
  k_wcvt<<<(Cc * Cc / 4 + 255) / 256, 256, 0, stream>>>(wqkv, wproj, wvb, wpb);
  k_q01<<<dim3(Bn * 2, 192), 256, 0, stream>>>(wqkv, x, q01d);
  k_u01<<<dim3(Bn * 2 * Hh, 3), 256, 0, stream>>>(wqkv, q01d, u01d);
  k_rlogits<<<dim3(Bn, 5, NCH), 256, 0, stream>>>(u01d, x, Ldp);
  k_rsoftmax<<<Bn * 2 * Hh, 256, 0, stream>>>(Ldp, Ld, Pb);
  k_rsums<<<Bn, 256, 0, stream>>>(Ld, suma, diffd);
  k_route<<<Bn, 256, 0, stream>>>(suma, diffd, rowcat);
  k_qg<<<Bn * 16, 256, 0, stream>>>(wqkv, x, rowcat, qf);
  k_ug<<<dim3(Hh, 6, 4), 256, 0, stream>>>(wqkv, qf, u16b);
  k_glogits_mfma<<<dim3(Bn, 3, 13), 256, 0, stream>>>(u16b, xbf, S);
  k_gsoftmax<<<Bn * 192, 256, 0, stream>>>(S, Pb);
  k_wsum_mfma<<<dim3(Bn, 4, 8), 256, 0, stream>>>(Pb, xT, wsumb);
  k_attnout_mfma<<<dim3(Hh, 18), 256, 0, stream>>>(wsumb, wvb, aob);
  k_proj_mfma<<<dim3(18, 12), 256, 0, stream>>>(aob, wpb, bproj, rowcat, gen, cls, box, out);
}

// Round 5
// 367.967 us; speedup vs baseline: 3.1307x; 1.2171x over previous
//
#include <hip/hip_runtime.h>
#include <math.h>

namespace {

constexpr int Bn = 16;    // batch
constexpr int NG = 1024;  // general tokens
constexpr int Cc = 768;   // channels
constexpr int Hh = 12;    // heads
constexpr int HD = 64;    // head dim
constexpr int Nn = 1026;  // total tokens (cls, box, general)
constexpr int NR = 18;    // rows we actually need: 0,1 + 16 routed
constexpr int NP = 1088;  // padded token count (17*64) for MFMA K / N
constexpr int NCH = 8;    // K-chunks for k_rlogits

typedef __attribute__((ext_vector_type(8))) short short8;
typedef __attribute__((ext_vector_type(4))) float f32x4;

__device__ inline unsigned short f2bf(float f) {
  unsigned u = __float_as_uint(f);
  unsigned r = u + 0x7FFFu + ((u >> 16) & 1u);
  return (unsigned short)(r >> 16);
}

// ---------------- K1: LayerNorm (fp64 accumulation) ----------------
__global__ __launch_bounds__(256) void k_ln(
    const float* __restrict__ gen, const float* __restrict__ cls,
    const float* __restrict__ box, const float* __restrict__ gamma,
    const float* __restrict__ beta, float* __restrict__ x,
    unsigned short* __restrict__ xbf) {
  int blk = blockIdx.x;
  int b = blk / Nn, n = blk % Nn;
  const float* src = (n == 0) ? cls + (size_t)b * Cc
                   : (n == 1) ? box + (size_t)b * Cc
                              : gen + ((size_t)b * NG + (n - 2)) * Cc;
  int t = threadIdx.x;
  float v0 = src[t], v1 = src[t + 256], v2 = src[t + 512];
  __shared__ double red[8];
  double s = (double)v0 + (double)v1 + (double)v2;
  for (int o = 32; o > 0; o >>= 1) s += __shfl_down(s, o, 64);
  int wid = t >> 6, lid = t & 63;
  if (lid == 0) red[wid] = s;
  __syncthreads();
  if (t == 0) red[4] = (red[0] + red[1] + red[2] + red[3]) / Cc;
  __syncthreads();
  double mean = red[4];
  double d0 = (double)v0 - mean, d1 = (double)v1 - mean, d2 = (double)v2 - mean;
  double sq = d0 * d0 + d1 * d1 + d2 * d2;
  for (int o = 32; o > 0; o >>= 1) sq += __shfl_down(sq, o, 64);
  __syncthreads();
  if (lid == 0) red[wid] = sq;
  __syncthreads();
  if (t == 0) {
    double var = (red[0] + red[1] + red[2] + red[3]) / Cc;
    red[5] = 1.0 / sqrt(var + 1e-5);
  }
  __syncthreads();
  double rs = red[5];
  float* dst = x + ((size_t)b * Nn + n) * Cc;
  unsigned short* dbf = xbf + ((size_t)b * NP + n) * Cc;
  float o0 = (float)(d0 * rs * (double)gamma[t]       + (double)beta[t]);
  float o1 = (float)(d1 * rs * (double)gamma[t + 256] + (double)beta[t + 256]);
  float o2 = (float)(d2 * rs * (double)gamma[t + 512] + (double)beta[t + 512]);
  dst[t] = o0; dst[t + 256] = o1; dst[t + 512] = o2;
  dbf[t] = f2bf(o0); dbf[t + 256] = f2bf(o1); dbf[t + 512] = f2bf(o2);
}

// ---------------- K1b: zero pad rows 1026..1087 of x_bf ----------------
__global__ __launch_bounds__(256) void k_padzero(unsigned short* __restrict__ xbf) {
  constexpr int PERB = (NP - Nn) * Cc / 2;  // uints per batch
  int idx = blockIdx.x * 256 + threadIdx.x;
  int total = Bn * PERB;
  for (int i = idx; i < total; i += gridDim.x * 256) {
    int b = i / PERB, r = i % PERB;
    unsigned int* p = (unsigned int*)(xbf + ((size_t)b * NP + Nn) * Cc);
    p[r] = 0u;
  }
}

// ---------------- K1c: transpose x_bf -> xT_bf [b][c][jpad] ----------------
__global__ __launch_bounds__(256) void k_xt(
    const unsigned short* __restrict__ xbf, unsigned short* __restrict__ xT) {
  int b = blockIdx.x, jt = blockIdx.y, ct = blockIdx.z;
  int j0 = jt * 64, c0 = ct * 64;
  __shared__ unsigned short ts[64][80];
  int t = threadIdx.x;
  #pragma unroll
  for (int l = 0; l < 2; l++) {
    int chunk = t + l * 256;
    int r = chunk >> 3, c8 = chunk & 7;
    uint4 v = *(const uint4*)(xbf + ((size_t)b * NP + j0 + r) * Cc + c0 + c8 * 8);
    *(uint4*)&ts[r][c8 * 8] = v;
  }
  __syncthreads();
  #pragma unroll
  for (int l = 0; l < 2; l++) {
    int chunk = t + l * 256;
    int orow = chunk >> 3, j8 = chunk & 7;
    unsigned short tmp[8];
    #pragma unroll
    for (int i = 0; i < 8; i++) tmp[i] = ts[j8 * 8 + i][orow];
    *(uint4*)(xT + ((size_t)b * Cc + c0 + orow) * NP + j0 + j8 * 8) = *(uint4*)tmp;
  }
}

// ---------------- K1d: convert Wq, Wv, Wproj to bf16 ----------------
__global__ __launch_bounds__(256) void k_wcvt(
    const float* __restrict__ wqkv, const float* __restrict__ wproj,
    unsigned short* __restrict__ wqb, unsigned short* __restrict__ wvb,
    unsigned short* __restrict__ wpb) {
  int i = (blockIdx.x * 256 + threadIdx.x) * 4;
  if (i >= Cc * Cc) return;
  const float* wq = wqkv;
  const float* wv = wqkv + (size_t)2 * Cc * Cc;
  float4 q = *(const float4*)(wq + i);
  float4 a = *(const float4*)(wv + i);
  float4 b = *(const float4*)(wproj + i);
  ushort4 oq, oa, ob;
  oq.x = f2bf(q.x); oq.y = f2bf(q.y); oq.z = f2bf(q.z); oq.w = f2bf(q.w);
  oa.x = f2bf(a.x); oa.y = f2bf(a.y); oa.z = f2bf(a.z); oa.w = f2bf(a.w);
  ob.x = f2bf(b.x); ob.y = f2bf(b.y); ob.z = f2bf(b.z); ob.w = f2bf(b.w);
  *(ushort4*)(wqb + i) = oq;
  *(ushort4*)(wvb + i) = oa;
  *(ushort4*)(wpb + i) = ob;
}

// ---------------- K1e: transpose Wk (fp32) -> WkT bf16 [c][hd] -------------
// grid (12, 12): hd-tile, c-tile (64x64 tiles)
__global__ __launch_bounds__(256) void k_wkt(
    const float* __restrict__ wqkv, unsigned short* __restrict__ wkTb) {
  int rt = blockIdx.x, ct = blockIdx.y;
  __shared__ unsigned short ts[64][72];
  int t = threadIdx.x;
  const float* src = wqkv + (size_t)Cc * Cc;
  #pragma unroll
  for (int l = 0; l < 4; l++) {
    int idx = t + l * 256;
    int r = idx >> 4, c4 = idx & 15;
    float4 v = *(const float4*)(src + (size_t)(rt * 64 + r) * Cc + ct * 64 + c4 * 4);
    ts[r][c4 * 4 + 0] = f2bf(v.x); ts[r][c4 * 4 + 1] = f2bf(v.y);
    ts[r][c4 * 4 + 2] = f2bf(v.z); ts[r][c4 * 4 + 3] = f2bf(v.w);
  }
  __syncthreads();
  #pragma unroll
  for (int l = 0; l < 2; l++) {
    int idx = t + l * 256;
    int r2 = idx >> 3, j8 = idx & 7;
    unsigned short tmp[8];
    #pragma unroll
    for (int i = 0; i < 8; i++) tmp[i] = ts[j8 * 8 + i][r2];
    *(uint4*)(wkTb + (size_t)(ct * 64 + r2) * Cc + rt * 64 + j8 * 8) = *(uint4*)tmp;
  }
}

// ---------------- K2: q rows 0,1 (fp64) — one wave per output ----------------
__global__ __launch_bounds__(256) void k_q01(
    const float* __restrict__ wqkv, const float* __restrict__ x,
    double* __restrict__ q01d) {
  int row = blockIdx.x;
  int b = row >> 1, i = row & 1;
  __shared__ float xl[Cc];
  const float* xr = x + ((size_t)b * Nn + i) * Cc;
  for (int c = threadIdx.x; c < Cc; c += 256) xl[c] = xr[c];
  __syncthreads();
  int w = threadIdx.x >> 6, lane = threadIdx.x & 63;
  int o = blockIdx.y * 4 + w;
  const float* wr = wqkv + (size_t)o * Cc + lane * 12;
  const float* xs = xl + lane * 12;
  double acc = 0;
  #pragma unroll
  for (int k = 0; k < 12; k++) acc += (double)wr[k] * (double)xs[k];
  for (int off = 32; off > 0; off >>= 1) acc += __shfl_down(acc, off, 64);
  if (lane == 0) q01d[(size_t)row * Cc + o] = acc;
}

// ---------------- K3: u rows 0,1 (fp64), c-split ----------------
__global__ __launch_bounds__(256) void k_u01(
    const float* __restrict__ wqkv, const double* __restrict__ q01d,
    double* __restrict__ u01d) {
  int blk = blockIdx.x;
  int h = blk % Hh; int i = (blk / Hh) & 1; int b = blk / (2 * Hh);
  __shared__ double qh[HD];
  const double* q = q01d + ((size_t)b * 2 + i) * Cc + h * HD;
  if (threadIdx.x < HD) qh[threadIdx.x] = q[threadIdx.x];
  __syncthreads();
  const float* wk = wqkv + (size_t)Cc * Cc;
  int c = blockIdx.y * 256 + threadIdx.x;
  double a0 = 0, a1 = 0, a2 = 0, a3 = 0;
  #pragma unroll 4
  for (int d = 0; d < HD; d += 4) {
    a0 += qh[d]     * (double)wk[(size_t)(h * HD + d) * Cc + c];
    a1 += qh[d + 1] * (double)wk[(size_t)(h * HD + d + 1) * Cc + c];
    a2 += qh[d + 2] * (double)wk[(size_t)(h * HD + d + 2) * Cc + c];
    a3 += qh[d + 3] * (double)wk[(size_t)(h * HD + d + 3) * Cc + c];
  }
  u01d[(((size_t)(b * 2 + i)) * Hh + h) * Cc + c] = (a0 + a1) + (a2 + a3);
}

// ---------------- K4: routing logits rows 0,1 (fp64, 8 K-chunks) -----------
__global__ __launch_bounds__(256) void k_rlogits(
    const double* __restrict__ u01d, const float* __restrict__ x,
    double* __restrict__ Ldp) {
  int b = blockIdx.x, jt = blockIdx.y, cch = blockIdx.z;
  int j0 = jt * 256;
  int t = threadIdx.x;
  int pl = t & 127;
  int g  = t >> 7;
  __shared__ float xtT[32][256];
  __shared__ double ut[24][32];
  double acc[12][2] = {};
  int cbase = cch * 96;
  for (int c0 = cbase; c0 < cbase + 96; c0 += 32) {
    {
      int j = j0 + t;
      if (j < Nn) {
        const float* xr = x + ((size_t)b * Nn + j) * Cc + c0;
        #pragma unroll
        for (int k = 0; k < 32; k += 4) {
          float4 v = *(const float4*)(xr + k);
          xtT[k][t] = v.x; xtT[k + 1][t] = v.y; xtT[k + 2][t] = v.z; xtT[k + 3][t] = v.w;
        }
      } else {
        for (int k = 0; k < 32; k++) xtT[k][t] = 0.f;
      }
    }
    for (int idx = t; idx < 24 * 32; idx += 256) {
      int r = idx >> 5, cc = idx & 31;
      ut[r][cc] = u01d[(((size_t)(b * 2 + (r / 12))) * Hh + (r % 12)) * Cc + c0 + cc];
    }
    __syncthreads();
    for (int cc = 0; cc < 32; cc++) {
      float2 xv = *(const float2*)&xtT[cc][pl * 2];
      double x0 = (double)xv.x, x1 = (double)xv.y;
      #pragma unroll
      for (int h = 0; h < 12; h++) {
        double uv = ut[g * 12 + h][cc];
        acc[h][0] += uv * x0;
        acc[h][1] += uv * x1;
      }
    }
    __syncthreads();
  }
  for (int h = 0; h < 12; h++) {
    #pragma unroll
    for (int k = 0; k < 2; k++) {
      int j = j0 + pl * 2 + k;
      if (j < Nn) {
        Ldp[(((size_t)cch * Bn + b) * 24 + g * 12 + h) * Nn + j] = acc[h][k] * 0.125;
      }
    }
  }
}

// ---------------- K5: sum partials + mask + softmax (fp64) ----------------
__global__ __launch_bounds__(256) void k_rsoftmax(
    const double* __restrict__ Ldp, double* __restrict__ Ld,
    unsigned short* __restrict__ Pb) {
  int blk = blockIdx.x;
  int h = blk % Hh; int i = (blk / Hh) & 1; int b = blk / (2 * Hh);
  double* row = Ld + (size_t)blk * Nn;
  unsigned short* prow = Pb + ((size_t)b * 216 + i * Hh + h) * NP;
  int t = threadIdx.x;
  size_t poff = ((size_t)b * 24 + i * 12 + h) * Nn;
  constexpr size_t PSTRIDE = (size_t)Bn * 24 * Nn;
  double lv[5];
  int cnt = 0;
  double mx = -1e300;
  for (int j = t; j < Nn; j += 256) {
    double L = 0;
    #pragma unroll
    for (int p = 0; p < NCH; p++) L += Ldp[(size_t)p * PSTRIDE + poff + j];
    if (i == 0 && j == 1) L = 0.0;
    if (i == 1 && j == 0) L = 0.0;
    lv[cnt++] = L;
    mx = fmax(mx, L);
  }
  __shared__ double sd[256];
  sd[t] = mx; __syncthreads();
  for (int st = 128; st > 0; st >>= 1) { if (t < st) sd[t] = fmax(sd[t], sd[t + st]); __syncthreads(); }
  mx = sd[0]; __syncthreads();
  double sum = 0;
  for (int k = 0; k < cnt; k++) { lv[k] = exp(lv[k] - mx); sum += lv[k]; }
  sd[t] = sum; __syncthreads();
  for (int st = 128; st > 0; st >>= 1) { if (t < st) sd[t] += sd[t + st]; __syncthreads(); }
  double inv = 1.0 / sd[0];
  int k = 0;
  for (int j = t; j < Nn; j += 256) {
    double p = lv[k++] * inv;
    row[j] = p;
    prow[j] = f2bf((float)p);
  }
  for (int j = Nn + t; j < NP; j += 256) prow[j] = 0;
}

// ---------------- K6: head means -> sum_a, diff (fp64) ----------------
__global__ __launch_bounds__(256) void k_rsums(
    const double* __restrict__ Ld, double* __restrict__ suma,
    double* __restrict__ diffd) {
  int b = blockIdx.x;
  for (int jg = threadIdx.x; jg < NG; jg += 256) {
    int j = jg + 2;
    double cs = 0, bs = 0;
    for (int h = 0; h < Hh; h++) {
      cs += Ld[(((size_t)(b * 2 + 0)) * Hh + h) * Nn + j];
      bs += Ld[(((size_t)(b * 2 + 1)) * Hh + h) * Nn + j];
    }
    cs /= 12.0; bs /= 12.0;
    suma[(size_t)b * NG + jg] = cs + bs;
    diffd[(size_t)b * NG + jg] = bs - cs;
  }
}

// ---------------- K7: routing — both cats concurrent, shuffle argmax -------
__global__ __launch_bounds__(256) void k_route(
    const double* __restrict__ suma, const double* __restrict__ diffd,
    int* __restrict__ rowcat) {
  int b = blockIdx.x, t = threadIdx.x;
  __shared__ double vals[NG];
  __shared__ unsigned char flags[NG];
  __shared__ double redv[4];
  __shared__ int redi[4];
  __shared__ int blist[16], clist[16];
  __shared__ double blv[16], clv[16];
  for (int j = t; j < NG; j += 256) {
    vals[j] = suma[(size_t)b * NG + j];
    flags[j] = diffd[(size_t)b * NG + j] > 0.0 ? 1 : 0;
  }
  __syncthreads();
  int half = t >> 7;
  int lt = t & 127;
  int wv = t >> 6;
  int lane = t & 63;
  for (int s = 0; s < 16; s++) {
    double bv = -1e300; int bi = 0x7fffffff;
    #pragma unroll
    for (int k = 0; k < 8; k++) {
      int j = lt * 8 + k;
      double v = vals[j];
      if (flags[j] == half && v > bv) { bv = v; bi = j; }
    }
    for (int off = 32; off > 0; off >>= 1) {
      double ov = __shfl_down(bv, off, 64);
      int oi = __shfl_down(bi, off, 64);
      if (ov > bv || (ov == bv && oi < bi)) { bv = ov; bi = oi; }
    }
    if (lane == 0) { redv[wv] = bv; redi[wv] = bi; }
    __syncthreads();
    if (lt == 0) {
      double v0 = redv[half * 2], v1 = redv[half * 2 + 1];
      int i0 = redi[half * 2], i1 = redi[half * 2 + 1];
      if (v1 > v0 || (v1 == v0 && i1 < i0)) { v0 = v1; i0 = i1; }
      int win = (v0 > -1e299) ? i0 : -1;
      if (half) { blist[s] = win; blv[s] = v0; }
      else      { clist[s] = win; clv[s] = v0; }
      if (win >= 0) vals[win] = -1e300;
    }
    __syncthreads();
  }
  if (t < 16) {
    int s = t;
    int bc = blist[s];
    int cl = clist[15 - s];
    double bvv = blv[s], cvv = clv[15 - s];
    int win;
    if (bc < 0 && cl < 0) win = -1;
    else if (bc < 0) win = cl;
    else if (cl < 0) win = bc;
    else {
      bool boxwins = (bvv < cvv) || (bvv == cvv && bc > cl);
      win = boxwins ? bc : cl;
    }
    int tok = (win >= 0) ? win : 0;
    rowcat[b * NR + 2 + s] = tok + 2;
  }
  if (t == 0) { rowcat[b * NR + 0] = 0; rowcat[b * NR + 1] = 1; }
}

// ---------------- K8: q for 16 gathered rows via MFMA ----------------
// grid (16, 12): mt (256 rows of (b,s)), ng; 4 waves -> nt = ng*4+wid (48 n-tiles)
__global__ __launch_bounds__(256) void k_qg_mfma(
    const unsigned short* __restrict__ xbf, const unsigned short* __restrict__ wqb,
    const int* __restrict__ rowcat, unsigned short* __restrict__ qb) {
  int mt = blockIdx.x, ng = blockIdx.y;
  int wid = threadIdx.x >> 6, lane = threadIdx.x & 63;
  int nt = ng * 4 + wid;
  int m = lane & 15, kg = lane >> 4;
  int rowi = mt * 16 + m;
  int b = rowi >> 4, s = rowi & 15;
  int tok = rowcat[b * NR + 2 + s];
  const unsigned short* abase = xbf + ((size_t)b * NP + tok) * Cc + kg * 8;
  const unsigned short* bbase = wqb + (size_t)(nt * 16 + m) * Cc + kg * 8;
  f32x4 acc = {0, 0, 0, 0};
  for (int k0 = 0; k0 < Cc; k0 += 32) {
    short8 a = *(const short8*)(abase + k0);
    short8 bf = *(const short8*)(bbase + k0);
    acc = __builtin_amdgcn_mfma_f32_16x16x32_bf16(a, bf, acc, 0, 0, 0);
  }
  int c = nt * 16 + m;
  #pragma unroll
  for (int r = 0; r < 4; r++) {
    int rowo = mt * 16 + kg * 4 + r;
    qb[(size_t)rowo * Cc + c] = f2bf(acc[r]);
  }
}

// ---------------- K9: u for gathered rows via MFMA ----------------
// grid (Hh, 16, 3): h, mt, ngz. Each wave: 4 n-tiles (acc[4]), K=64 (2 steps).
__global__ __launch_bounds__(256) void k_ug_mfma(
    const unsigned short* __restrict__ qb, const unsigned short* __restrict__ wkTb,
    unsigned short* __restrict__ u16b) {
  int h = blockIdx.x, mt = blockIdx.y, ngz = blockIdx.z;
  int wid = threadIdx.x >> 6, lane = threadIdx.x & 63;
  int m = lane & 15, kg = lane >> 4;
  int rowi = mt * 16 + m;
  const unsigned short* abase = qb + (size_t)rowi * Cc + h * HD + kg * 8;
  f32x4 acc[4] = {{0,0,0,0},{0,0,0,0},{0,0,0,0},{0,0,0,0}};
  #pragma unroll
  for (int k0 = 0; k0 < HD; k0 += 32) {
    short8 a = *(const short8*)(abase + k0);
    #pragma unroll
    for (int t = 0; t < 4; t++) {
      int c = ngz * 256 + (wid * 4 + t) * 16 + m;
      short8 bf = *(const short8*)(wkTb + (size_t)c * Cc + h * HD + kg * 8 + k0);
      acc[t] = __builtin_amdgcn_mfma_f32_16x16x32_bf16(a, bf, acc[t], 0, 0, 0);
    }
  }
  #pragma unroll
  for (int t = 0; t < 4; t++) {
    int c = ngz * 256 + (wid * 4 + t) * 16 + m;
    #pragma unroll
    for (int r = 0; r < 4; r++) {
      int row = mt * 16 + kg * 4 + r;
      int b = row >> 4, s = row & 15;
      u16b[((size_t)b * 192 + s * Hh + h) * Cc + c] = f2bf(acc[t][r]);
    }
  }
}

// ---------------- K10: gathered logits via MFMA ----------------
__global__ __launch_bounds__(256) void k_glogits_mfma(
    const unsigned short* __restrict__ u16b, const unsigned short* __restrict__ xbf,
    float* __restrict__ S) {
  int b = blockIdx.x, mg = blockIdx.y, nz = blockIdx.z;
  int wid = threadIdx.x >> 6, lane = threadIdx.x & 63;
  int mtile = mg * 4 + wid;
  int m = lane & 15, kg = lane >> 4;
  int row = mtile * 16 + m;
  const unsigned short* abase = u16b + ((size_t)b * 192 + row) * Cc + kg * 8;
  const unsigned short* bbase = xbf + (size_t)b * NP * Cc + kg * 8;
  f32x4 acc[5] = {{0,0,0,0},{0,0,0,0},{0,0,0,0},{0,0,0,0},{0,0,0,0}};
  int jb = nz * 80 + m;
  for (int k0 = 0; k0 < Cc; k0 += 32) {
    short8 a = *(const short8*)(abase + k0);
    #pragma unroll
    for (int t = 0; t < 5; t++) {
      short8 bf = *(const short8*)(bbase + (size_t)(jb + t * 16) * Cc + k0);
      acc[t] = __builtin_amdgcn_mfma_f32_16x16x32_bf16(a, bf, acc[t], 0, 0, 0);
    }
  }
  #pragma unroll
  for (int t = 0; t < 5; t++) {
    int col = nz * 80 + t * 16 + m;
    #pragma unroll
    for (int r = 0; r < 4; r++) {
      int rr = mtile * 16 + kg * 4 + r;
      S[((size_t)b * 192 + rr) * 1040 + col] = acc[t][r] * 0.125f;
    }
  }
}

// ---------------- K11: softmax for gathered rows (reads S, writes bf16 P) --
__global__ __launch_bounds__(256) void k_gsoftmax(
    const float* __restrict__ S, unsigned short* __restrict__ Pb) {
  int blk = blockIdx.x;
  int b = blk / 192, r = blk % 192;
  const float* row = S + ((size_t)b * 192 + r) * 1040;
  unsigned short* prow = Pb + ((size_t)b * 216 + 24 + r) * NP;
  int t = threadIdx.x;
  __shared__ float sd[256];
  float mx = -1e30f;
  for (int j = t; j < Nn; j += 256) mx = fmaxf(mx, row[j]);
  sd[t] = mx; __syncthreads();
  for (int st = 128; st > 0; st >>= 1) { if (t < st) sd[t] = fmaxf(sd[t], sd[t + st]); __syncthreads(); }
  mx = sd[0]; __syncthreads();
  float sum = 0;
  for (int j = t; j < Nn; j += 256) sum += __expf(row[j] - mx);
  sd[t] = sum; __syncthreads();
  for (int st = 128; st > 0; st >>= 1) { if (t < st) sd[t] += sd[t + st]; __syncthreads(); }
  float inv = 1.0f / sd[0];
  for (int j = t; j < NP; j += 256) {
    prow[j] = (j < Nn) ? f2bf(__expf(row[j] - mx) * inv) : (unsigned short)0;
  }
}

// ---------------- K12: wsum via MFMA (bf16 out) ----------------
__global__ __launch_bounds__(256) void k_wsum_mfma(
    const unsigned short* __restrict__ Pb, const unsigned short* __restrict__ xT,
    unsigned short* __restrict__ wsumb) {
  int b = blockIdx.x, mg = blockIdx.y, nz = blockIdx.z;
  int wid = threadIdx.x >> 6, lane = threadIdx.x & 63;
  int mtile = mg * 4 + wid;
  int m = lane & 15, kg = lane >> 4;
  int row = mtile * 16 + m;
  int rowc = row < 216 ? row : 215;
  const unsigned short* abase = Pb + ((size_t)b * 216 + rowc) * NP + kg * 8;
  const unsigned short* bbase = xT + (size_t)b * Cc * NP + kg * 8;
  f32x4 acc[6] = {{0,0,0,0},{0,0,0,0},{0,0,0,0},{0,0,0,0},{0,0,0,0},{0,0,0,0}};
  int cb = nz * 96 + m;
  for (int k0 = 0; k0 < NP; k0 += 32) {
    short8 a = *(const short8*)(abase + k0);
    #pragma unroll
    for (int t = 0; t < 6; t++) {
      short8 bf = *(const short8*)(bbase + (size_t)(cb + t * 16) * NP + k0);
      acc[t] = __builtin_amdgcn_mfma_f32_16x16x32_bf16(a, bf, acc[t], 0, 0, 0);
    }
  }
  #pragma unroll
  for (int t = 0; t < 6; t++) {
    int col = nz * 96 + t * 16 + m;
    #pragma unroll
    for (int r = 0; r < 4; r++) {
      int rr = mtile * 16 + kg * 4 + r;
      if (rr < 216) wsumb[((size_t)b * 216 + rr) * Cc + col] = f2bf(acc[t][r]);
    }
  }
}

// ---------------- K13: attnout = Wv * wsum via MFMA ----------------
__global__ __launch_bounds__(256) void k_attnout_mfma(
    const unsigned short* __restrict__ wsumb, const unsigned short* __restrict__ wvb,
    unsigned short* __restrict__ aob) {
  int h = blockIdx.x, mt = blockIdx.y;
  int wid = threadIdx.x >> 6, lane = threadIdx.x & 63;
  int m = lane & 15, kg = lane >> 4;
  int row = mt * 16 + m;
  int b = row / NR, i = row % NR;
  const unsigned short* abase = wsumb + ((size_t)b * 216 + i * 12 + h) * Cc + kg * 8;
  const unsigned short* bbase = wvb + (size_t)(h * HD + wid * 16 + m) * Cc + kg * 8;
  f32x4 acc = {0, 0, 0, 0};
  for (int k0 = 0; k0 < Cc; k0 += 32) {
    short8 a = *(const short8*)(abase + k0);
    short8 bf = *(const short8*)(bbase + k0);
    acc = __builtin_amdgcn_mfma_f32_16x16x32_bf16(a, bf, acc, 0, 0, 0);
  }
  #pragma unroll
  for (int r = 0; r < 4; r++) {
    int orow = mt * 16 + kg * 4 + r;
    int ocol = h * HD + wid * 16 + m;
    aob[(size_t)orow * Cc + ocol] = f2bf(acc[r]);
  }
}

// ---------------- K14: proj via MFMA + bias + residual + scatter ----------
__global__ __launch_bounds__(256) void k_proj_mfma(
    const unsigned short* __restrict__ aob, const unsigned short* __restrict__ wpb,
    const float* __restrict__ bproj, const int* __restrict__ rowcat,
    const float* __restrict__ gen, const float* __restrict__ cls,
    const float* __restrict__ box, float* __restrict__ out) {
  int mt = blockIdx.x, ng = blockIdx.y;
  int wid = threadIdx.x >> 6, lane = threadIdx.x & 63;
  int nt = ng * 4 + wid;
  int m = lane & 15, kg = lane >> 4;
  const unsigned short* abase = aob + (size_t)(mt * 16 + m) * Cc + kg * 8;
  const unsigned short* bbase = wpb + (size_t)(nt * 16 + m) * Cc + kg * 8;
  f32x4 acc = {0, 0, 0, 0};
  for (int k0 = 0; k0 < Cc; k0 += 32) {
    short8 a = *(const short8*)(abase + k0);
    short8 bf = *(const short8*)(bbase + k0);
    acc = __builtin_amdgcn_mfma_f32_16x16x32_bf16(a, bf, acc, 0, 0, 0);
  }
  int c = nt * 16 + m;
  float bp = bproj[c];
  #pragma unroll
  for (int r = 0; r < 4; r++) {
    int bi = mt * 16 + kg * 4 + r;
    int b = bi / NR, i = bi % NR;
    int tok = rowcat[b * NR + i];
    const float* src = (tok == 0) ? cls + (size_t)b * Cc
                     : (tok == 1) ? box + (size_t)b * Cc
                                  : gen + ((size_t)b * NG + tok - 2) * Cc;
    float val = acc[r] + bp + src[c];
    float* dst;
    if (i == 0)       dst = out + ((size_t)b * 9 + 0) * Cc;
    else if (i == 1)  dst = out + (size_t)Bn * 9 * Cc + ((size_t)b * 9 + 0) * Cc;
    else if (i < 10)  dst = out + ((size_t)b * 9 + (i - 1)) * Cc;
    else              dst = out + (size_t)Bn * 9 * Cc + ((size_t)b * 9 + (i - 9)) * Cc;
    dst[c] = val;
  }
}

}  // namespace

extern "C" void kernel_launch(void* const* d_in, const int* in_sizes, int n_in,
                              void* d_out, int out_size, void* d_ws, size_t ws_size,
                              hipStream_t stream) {
  (void)in_sizes; (void)n_in; (void)out_size; (void)ws_size;
  const float* gen   = (const float*)d_in[0];
  const float* cls   = (const float*)d_in[1];
  const float* box   = (const float*)d_in[2];
  const float* wqkv  = (const float*)d_in[3];
  const float* wproj = (const float*)d_in[4];
  const float* bproj = (const float*)d_in[5];
  const float* gamma = (const float*)d_in[6];
  const float* beta  = (const float*)d_in[7];
  float* out = (float*)d_out;

  char* ws = (char*)d_ws;
  size_t off = 0;
  auto alloc = [&](size_t bytes) { void* p = ws + off; off += (bytes + 255) & ~(size_t)255; return p; };
  float* x             = (float*)alloc((size_t)Bn * Nn * Cc * 4);
  unsigned short* xbf  = (unsigned short*)alloc((size_t)Bn * NP * Cc * 2);
  unsigned short* xT   = (unsigned short*)alloc((size_t)Bn * Cc * NP * 2);
  unsigned short* qb   = (unsigned short*)alloc((size_t)256 * Cc * 2);
  unsigned short* u16b = (unsigned short*)alloc((size_t)Bn * 192 * Cc * 2);
  float* S             = (float*)alloc((size_t)Bn * 192 * 1040 * 4);
  unsigned short* Pb   = (unsigned short*)alloc((size_t)Bn * 216 * NP * 2);
  unsigned short* wsumb= (unsigned short*)alloc((size_t)Bn * 216 * Cc * 2);
  unsigned short* aob  = (unsigned short*)alloc((size_t)288 * Cc * 2);
  unsigned short* wqb  = (unsigned short*)alloc((size_t)Cc * Cc * 2);
  unsigned short* wvb  = (unsigned short*)alloc((size_t)Cc * Cc * 2);
  unsigned short* wpb  = (unsigned short*)alloc((size_t)Cc * Cc * 2);
  unsigned short* wkTb = (unsigned short*)alloc((size_t)Cc * Cc * 2);
  double* q01d         = (double*)alloc((size_t)Bn * 2 * Cc * 8);
  double* u01d         = (double*)alloc((size_t)Bn * 2 * Hh * Cc * 8);
  double* Ld           = (double*)alloc((size_t)Bn * 2 * Hh * Nn * 8);
  double* Ldp          = (double*)alloc((size_t)NCH * Bn * 24 * Nn * 8);
  double* suma         = (double*)alloc((size_t)Bn * NG * 8);
  double* diffd        = (double*)alloc((size_t)Bn * NG * 8);
  int* rowcat          = (int*)alloc((size_t)Bn * NR * 4);

  k_ln<<<Bn * Nn, 256, 0, stream>>>(gen, cls, box, gamma, beta, x, xbf);
  k_padzero<<<48, 256, 0, stream>>>(xbf);
  k_xt<<<dim3(Bn, 17, 12), 256, 0, stream>>>(xbf, xT);
  k_wcvt<<<(Cc * Cc / 4 + 255) / 256, 256, 0, stream>>>(wqkv, wproj, wqb, wvb, wpb);
  k_wkt<<<dim3(12, 12), 256, 0, stream>>>(wqkv, wkTb);
  k_q01<<<dim3(Bn * 2, 192), 256, 0, stream>>>(wqkv, x, q01d);
  k_u01<<<dim3(Bn * 2 * Hh, 3), 256, 0, stream>>>(wqkv, q01d, u01d);
  k_rlogits<<<dim3(Bn, 5, NCH), 256, 0, stream>>>(u01d, x, Ldp);
  k_rsoftmax<<<Bn * 2 * Hh, 256, 0, stream>>>(Ldp, Ld, Pb);
  k_rsums<<<Bn, 256, 0, stream>>>(Ld, suma, diffd);
  k_route<<<Bn, 256, 0, stream>>>(suma, diffd, rowcat);
  k_qg_mfma<<<dim3(16, 12), 256, 0, stream>>>(xbf, wqb, rowcat, qb);
  k_ug_mfma<<<dim3(Hh, 16, 3), 256, 0, stream>>>(qb, wkTb, u16b);
  k_glogits_mfma<<<dim3(Bn, 3, 13), 256, 0, stream>>>(u16b, xbf, S);
  k_gsoftmax<<<Bn * 192, 256, 0, stream>>>(S, Pb);
  k_wsum_mfma<<<dim3(Bn, 4, 8), 256, 0, stream>>>(Pb, xT, wsumb);
  k_attnout_mfma<<<dim3(Hh, 18), 256, 0, stream>>>(wsumb, wvb, aob);
  k_proj_mfma<<<dim3(18, 12), 256, 0, stream>>>(aob, wpb, bproj, rowcat, gen, cls, box, out);
}

// Round 6
// 300.380 us; speedup vs baseline: 3.8351x; 1.2250x over previous
//
#include <hip/hip_runtime.h>
#include <math.h>

namespace {

constexpr int Bn = 16;    // batch
constexpr int NG = 1024;  // general tokens
constexpr int Cc = 768;   // channels
constexpr int Hh = 12;    // heads
constexpr int HD = 64;    // head dim
constexpr int Nn = 1026;  // total tokens (cls, box, general)
constexpr int NR = 18;    // rows we actually need: 0,1 + 16 routed
constexpr int NPK = 1152; // padded token count (9*128) for MFMA K / N tiles
constexpr int NCH = 8;    // K-chunks for k_rlogits

typedef __attribute__((ext_vector_type(8))) short short8;
typedef __attribute__((ext_vector_type(4))) float f32x4;

__device__ inline unsigned short f2bf(float f) {
  unsigned u = __float_as_uint(f);
  unsigned r = u + 0x7FFFu + ((u >> 16) & 1u);
  return (unsigned short)(r >> 16);
}

// ---------------- K1: LayerNorm (fp64 accumulation) ----------------
__global__ __launch_bounds__(256) void k_ln(
    const float* __restrict__ gen, const float* __restrict__ cls,
    const float* __restrict__ box, const float* __restrict__ gamma,
    const float* __restrict__ beta, float* __restrict__ x,
    unsigned short* __restrict__ xbf) {
  int blk = blockIdx.x;
  int b = blk / Nn, n = blk % Nn;
  const float* src = (n == 0) ? cls + (size_t)b * Cc
                   : (n == 1) ? box + (size_t)b * Cc
                              : gen + ((size_t)b * NG + (n - 2)) * Cc;
  int t = threadIdx.x;
  float v0 = src[t], v1 = src[t + 256], v2 = src[t + 512];
  __shared__ double red[8];
  double s = (double)v0 + (double)v1 + (double)v2;
  for (int o = 32; o > 0; o >>= 1) s += __shfl_down(s, o, 64);
  int wid = t >> 6, lid = t & 63;
  if (lid == 0) red[wid] = s;
  __syncthreads();
  if (t == 0) red[4] = (red[0] + red[1] + red[2] + red[3]) / Cc;
  __syncthreads();
  double mean = red[4];
  double d0 = (double)v0 - mean, d1 = (double)v1 - mean, d2 = (double)v2 - mean;
  double sq = d0 * d0 + d1 * d1 + d2 * d2;
  for (int o = 32; o > 0; o >>= 1) sq += __shfl_down(sq, o, 64);
  __syncthreads();
  if (lid == 0) red[wid] = sq;
  __syncthreads();
  if (t == 0) {
    double var = (red[0] + red[1] + red[2] + red[3]) / Cc;
    red[5] = 1.0 / sqrt(var + 1e-5);
  }
  __syncthreads();
  double rs = red[5];
  float* dst = x + ((size_t)b * Nn + n) * Cc;
  unsigned short* dbf = xbf + ((size_t)b * NPK + n) * Cc;
  float o0 = (float)(d0 * rs * (double)gamma[t]       + (double)beta[t]);
  float o1 = (float)(d1 * rs * (double)gamma[t + 256] + (double)beta[t + 256]);
  float o2 = (float)(d2 * rs * (double)gamma[t + 512] + (double)beta[t + 512]);
  dst[t] = o0; dst[t + 256] = o1; dst[t + 512] = o2;
  dbf[t] = f2bf(o0); dbf[t + 256] = f2bf(o1); dbf[t + 512] = f2bf(o2);
}

// ---------------- K1b: zero pad rows 1026..1151 of x_bf ----------------
__global__ __launch_bounds__(256) void k_padzero(unsigned short* __restrict__ xbf) {
  constexpr int PERB = (NPK - Nn) * Cc / 2;  // uints per batch
  int idx = blockIdx.x * 256 + threadIdx.x;
  int total = Bn * PERB;
  for (int i = idx; i < total; i += gridDim.x * 256) {
    int b = i / PERB, r = i % PERB;
    unsigned int* p = (unsigned int*)(xbf + ((size_t)b * NPK + Nn) * Cc);
    p[r] = 0u;
  }
}

// ---------------- K1c: transpose x_bf -> xT_bf [b][c][jpad] ----------------
__global__ __launch_bounds__(256) void k_xt(
    const unsigned short* __restrict__ xbf, unsigned short* __restrict__ xT) {
  int b = blockIdx.x, jt = blockIdx.y, ct = blockIdx.z;
  int j0 = jt * 64, c0 = ct * 64;
  __shared__ unsigned short ts[64][80];
  int t = threadIdx.x;
  #pragma unroll
  for (int l = 0; l < 2; l++) {
    int chunk = t + l * 256;
    int r = chunk >> 3, c8 = chunk & 7;
    uint4 v = *(const uint4*)(xbf + ((size_t)b * NPK + j0 + r) * Cc + c0 + c8 * 8);
    *(uint4*)&ts[r][c8 * 8] = v;
  }
  __syncthreads();
  #pragma unroll
  for (int l = 0; l < 2; l++) {
    int chunk = t + l * 256;
    int orow = chunk >> 3, j8 = chunk & 7;
    unsigned short tmp[8];
    #pragma unroll
    for (int i = 0; i < 8; i++) tmp[i] = ts[j8 * 8 + i][orow];
    *(uint4*)(xT + ((size_t)b * Cc + c0 + orow) * NPK + j0 + j8 * 8) = *(uint4*)tmp;
  }
}

// ---------------- K1d: convert Wq, Wv, Wproj to bf16 ----------------
__global__ __launch_bounds__(256) void k_wcvt(
    const float* __restrict__ wqkv, const float* __restrict__ wproj,
    unsigned short* __restrict__ wqb, unsigned short* __restrict__ wvb,
    unsigned short* __restrict__ wpb) {
  int i = (blockIdx.x * 256 + threadIdx.x) * 4;
  if (i >= Cc * Cc) return;
  const float* wq = wqkv;
  const float* wv = wqkv + (size_t)2 * Cc * Cc;
  float4 q = *(const float4*)(wq + i);
  float4 a = *(const float4*)(wv + i);
  float4 b = *(const float4*)(wproj + i);
  ushort4 oq, oa, ob;
  oq.x = f2bf(q.x); oq.y = f2bf(q.y); oq.z = f2bf(q.z); oq.w = f2bf(q.w);
  oa.x = f2bf(a.x); oa.y = f2bf(a.y); oa.z = f2bf(a.z); oa.w = f2bf(a.w);
  ob.x = f2bf(b.x); ob.y = f2bf(b.y); ob.z = f2bf(b.z); ob.w = f2bf(b.w);
  *(ushort4*)(wqb + i) = oq;
  *(ushort4*)(wvb + i) = oa;
  *(ushort4*)(wpb + i) = ob;
}

// ---------------- K1e: transpose Wk (fp32) -> WkT bf16 [c][hd] -------------
__global__ __launch_bounds__(256) void k_wkt(
    const float* __restrict__ wqkv, unsigned short* __restrict__ wkTb) {
  int rt = blockIdx.x, ct = blockIdx.y;
  __shared__ unsigned short ts[64][72];
  int t = threadIdx.x;
  const float* src = wqkv + (size_t)Cc * Cc;
  #pragma unroll
  for (int l = 0; l < 4; l++) {
    int idx = t + l * 256;
    int r = idx >> 4, c4 = idx & 15;
    float4 v = *(const float4*)(src + (size_t)(rt * 64 + r) * Cc + ct * 64 + c4 * 4);
    ts[r][c4 * 4 + 0] = f2bf(v.x); ts[r][c4 * 4 + 1] = f2bf(v.y);
    ts[r][c4 * 4 + 2] = f2bf(v.z); ts[r][c4 * 4 + 3] = f2bf(v.w);
  }
  __syncthreads();
  #pragma unroll
  for (int l = 0; l < 2; l++) {
    int idx = t + l * 256;
    int r2 = idx >> 3, j8 = idx & 7;
    unsigned short tmp[8];
    #pragma unroll
    for (int i = 0; i < 8; i++) tmp[i] = ts[j8 * 8 + i][r2];
    *(uint4*)(wkTb + (size_t)(ct * 64 + r2) * Cc + rt * 64 + j8 * 8) = *(uint4*)tmp;
  }
}

// ---------------- K2: q rows 0,1 (fp64) — one wave per output ----------------
__global__ __launch_bounds__(256) void k_q01(
    const float* __restrict__ wqkv, const float* __restrict__ x,
    double* __restrict__ q01d) {
  int row = blockIdx.x;
  int b = row >> 1, i = row & 1;
  __shared__ float xl[Cc];
  const float* xr = x + ((size_t)b * Nn + i) * Cc;
  for (int c = threadIdx.x; c < Cc; c += 256) xl[c] = xr[c];
  __syncthreads();
  int w = threadIdx.x >> 6, lane = threadIdx.x & 63;
  int o = blockIdx.y * 4 + w;
  const float* wr = wqkv + (size_t)o * Cc + lane * 12;
  const float* xs = xl + lane * 12;
  double acc = 0;
  #pragma unroll
  for (int k = 0; k < 12; k++) acc += (double)wr[k] * (double)xs[k];
  for (int off = 32; off > 0; off >>= 1) acc += __shfl_down(acc, off, 64);
  if (lane == 0) q01d[(size_t)row * Cc + o] = acc;
}

// ---------------- K3: u rows 0,1 (fp64), c-split ----------------
__global__ __launch_bounds__(256) void k_u01(
    const float* __restrict__ wqkv, const double* __restrict__ q01d,
    double* __restrict__ u01d) {
  int blk = blockIdx.x;
  int h = blk % Hh; int i = (blk / Hh) & 1; int b = blk / (2 * Hh);
  __shared__ double qh[HD];
  const double* q = q01d + ((size_t)b * 2 + i) * Cc + h * HD;
  if (threadIdx.x < HD) qh[threadIdx.x] = q[threadIdx.x];
  __syncthreads();
  const float* wk = wqkv + (size_t)Cc * Cc;
  int c = blockIdx.y * 256 + threadIdx.x;
  double a0 = 0, a1 = 0, a2 = 0, a3 = 0;
  #pragma unroll 4
  for (int d = 0; d < HD; d += 4) {
    a0 += qh[d]     * (double)wk[(size_t)(h * HD + d) * Cc + c];
    a1 += qh[d + 1] * (double)wk[(size_t)(h * HD + d + 1) * Cc + c];
    a2 += qh[d + 2] * (double)wk[(size_t)(h * HD + d + 2) * Cc + c];
    a3 += qh[d + 3] * (double)wk[(size_t)(h * HD + d + 3) * Cc + c];
  }
  u01d[(((size_t)(b * 2 + i)) * Hh + h) * Cc + c] = (a0 + a1) + (a2 + a3);
}

// ---------------- K4: routing logits rows 0,1 (fp64, 8 K-chunks) -----------
__global__ __launch_bounds__(256) void k_rlogits(
    const double* __restrict__ u01d, const float* __restrict__ x,
    double* __restrict__ Ldp) {
  int b = blockIdx.x, jt = blockIdx.y, cch = blockIdx.z;
  int j0 = jt * 256;
  int t = threadIdx.x;
  int pl = t & 127;
  int g  = t >> 7;
  __shared__ float xtT[32][256];
  __shared__ double ut[24][32];
  double acc[12][2] = {};
  int cbase = cch * 96;
  for (int c0 = cbase; c0 < cbase + 96; c0 += 32) {
    {
      int j = j0 + t;
      if (j < Nn) {
        const float* xr = x + ((size_t)b * Nn + j) * Cc + c0;
        #pragma unroll
        for (int k = 0; k < 32; k += 4) {
          float4 v = *(const float4*)(xr + k);
          xtT[k][t] = v.x; xtT[k + 1][t] = v.y; xtT[k + 2][t] = v.z; xtT[k + 3][t] = v.w;
        }
      } else {
        for (int k = 0; k < 32; k++) xtT[k][t] = 0.f;
      }
    }
    for (int idx = t; idx < 24 * 32; idx += 256) {
      int r = idx >> 5, cc = idx & 31;
      ut[r][cc] = u01d[(((size_t)(b * 2 + (r / 12))) * Hh + (r % 12)) * Cc + c0 + cc];
    }
    __syncthreads();
    for (int cc = 0; cc < 32; cc++) {
      float2 xv = *(const float2*)&xtT[cc][pl * 2];
      double x0 = (double)xv.x, x1 = (double)xv.y;
      #pragma unroll
      for (int h = 0; h < 12; h++) {
        double uv = ut[g * 12 + h][cc];
        acc[h][0] += uv * x0;
        acc[h][1] += uv * x1;
      }
    }
    __syncthreads();
  }
  for (int h = 0; h < 12; h++) {
    #pragma unroll
    for (int k = 0; k < 2; k++) {
      int j = j0 + pl * 2 + k;
      if (j < Nn) {
        Ldp[(((size_t)cch * Bn + b) * 24 + g * 12 + h) * Nn + j] = acc[h][k] * 0.125;
      }
    }
  }
}

// ---------------- K5: sum partials + mask + softmax (fp64) ----------------
__global__ __launch_bounds__(256) void k_rsoftmax(
    const double* __restrict__ Ldp, double* __restrict__ Ld,
    unsigned short* __restrict__ Pb) {
  int blk = blockIdx.x;
  int h = blk % Hh; int i = (blk / Hh) & 1; int b = blk / (2 * Hh);
  double* row = Ld + (size_t)blk * Nn;
  unsigned short* prow = Pb + ((size_t)b * 216 + i * Hh + h) * NPK;
  int t = threadIdx.x;
  size_t poff = ((size_t)b * 24 + i * 12 + h) * Nn;
  constexpr size_t PSTRIDE = (size_t)Bn * 24 * Nn;
  double lv[5];
  int cnt = 0;
  double mx = -1e300;
  for (int j = t; j < Nn; j += 256) {
    double L = 0;
    #pragma unroll
    for (int p = 0; p < NCH; p++) L += Ldp[(size_t)p * PSTRIDE + poff + j];
    if (i == 0 && j == 1) L = 0.0;
    if (i == 1 && j == 0) L = 0.0;
    lv[cnt++] = L;
    mx = fmax(mx, L);
  }
  __shared__ double sd[256];
  sd[t] = mx; __syncthreads();
  for (int st = 128; st > 0; st >>= 1) { if (t < st) sd[t] = fmax(sd[t], sd[t + st]); __syncthreads(); }
  mx = sd[0]; __syncthreads();
  double sum = 0;
  for (int k = 0; k < cnt; k++) { lv[k] = exp(lv[k] - mx); sum += lv[k]; }
  sd[t] = sum; __syncthreads();
  for (int st = 128; st > 0; st >>= 1) { if (t < st) sd[t] += sd[t + st]; __syncthreads(); }
  double inv = 1.0 / sd[0];
  int k = 0;
  for (int j = t; j < Nn; j += 256) {
    double p = lv[k++] * inv;
    row[j] = p;
    prow[j] = f2bf((float)p);
  }
  for (int j = Nn + t; j < NPK; j += 256) prow[j] = 0;
}

// ---------------- K6: head means -> sum_a, diff (fp64) ----------------
__global__ __launch_bounds__(256) void k_rsums(
    const double* __restrict__ Ld, double* __restrict__ suma,
    double* __restrict__ diffd) {
  int b = blockIdx.x;
  for (int jg = threadIdx.x; jg < NG; jg += 256) {
    int j = jg + 2;
    double cs = 0, bs = 0;
    for (int h = 0; h < Hh; h++) {
      cs += Ld[(((size_t)(b * 2 + 0)) * Hh + h) * Nn + j];
      bs += Ld[(((size_t)(b * 2 + 1)) * Hh + h) * Nn + j];
    }
    cs /= 12.0; bs /= 12.0;
    suma[(size_t)b * NG + jg] = cs + bs;
    diffd[(size_t)b * NG + jg] = bs - cs;
  }
}

// ---------------- K7: routing — both cats concurrent, shuffle argmax -------
__global__ __launch_bounds__(256) void k_route(
    const double* __restrict__ suma, const double* __restrict__ diffd,
    int* __restrict__ rowcat) {
  int b = blockIdx.x, t = threadIdx.x;
  __shared__ double vals[NG];
  __shared__ unsigned char flags[NG];
  __shared__ double redv[4];
  __shared__ int redi[4];
  __shared__ int blist[16], clist[16];
  __shared__ double blv[16], clv[16];
  for (int j = t; j < NG; j += 256) {
    vals[j] = suma[(size_t)b * NG + j];
    flags[j] = diffd[(size_t)b * NG + j] > 0.0 ? 1 : 0;
  }
  __syncthreads();
  int half = t >> 7;
  int lt = t & 127;
  int wv = t >> 6;
  int lane = t & 63;
  for (int s = 0; s < 16; s++) {
    double bv = -1e300; int bi = 0x7fffffff;
    #pragma unroll
    for (int k = 0; k < 8; k++) {
      int j = lt * 8 + k;
      double v = vals[j];
      if (flags[j] == half && v > bv) { bv = v; bi = j; }
    }
    for (int off = 32; off > 0; off >>= 1) {
      double ov = __shfl_down(bv, off, 64);
      int oi = __shfl_down(bi, off, 64);
      if (ov > bv || (ov == bv && oi < bi)) { bv = ov; bi = oi; }
    }
    if (lane == 0) { redv[wv] = bv; redi[wv] = bi; }
    __syncthreads();
    if (lt == 0) {
      double v0 = redv[half * 2], v1 = redv[half * 2 + 1];
      int i0 = redi[half * 2], i1 = redi[half * 2 + 1];
      if (v1 > v0 || (v1 == v0 && i1 < i0)) { v0 = v1; i0 = i1; }
      int win = (v0 > -1e299) ? i0 : -1;
      if (half) { blist[s] = win; blv[s] = v0; }
      else      { clist[s] = win; clv[s] = v0; }
      if (win >= 0) vals[win] = -1e300;
    }
    __syncthreads();
  }
  if (t < 16) {
    int s = t;
    int bc = blist[s];
    int cl = clist[15 - s];
    double bvv = blv[s], cvv = clv[15 - s];
    int win;
    if (bc < 0 && cl < 0) win = -1;
    else if (bc < 0) win = cl;
    else if (cl < 0) win = bc;
    else {
      bool boxwins = (bvv < cvv) || (bvv == cvv && bc > cl);
      win = boxwins ? bc : cl;
    }
    int tok = (win >= 0) ? win : 0;
    rowcat[b * NR + 2 + s] = tok + 2;
  }
  if (t == 0) { rowcat[b * NR + 0] = 0; rowcat[b * NR + 1] = 1; }
}

// ---------------- K8: q for 16 gathered rows via MFMA ----------------
__global__ __launch_bounds__(256) void k_qg_mfma(
    const unsigned short* __restrict__ xbf, const unsigned short* __restrict__ wqb,
    const int* __restrict__ rowcat, unsigned short* __restrict__ qb) {
  int mt = blockIdx.x, ng = blockIdx.y;
  int wid = threadIdx.x >> 6, lane = threadIdx.x & 63;
  int nt = ng * 4 + wid;
  int m = lane & 15, kg = lane >> 4;
  int rowi = mt * 16 + m;
  int b = rowi >> 4, s = rowi & 15;
  int tok = rowcat[b * NR + 2 + s];
  const unsigned short* abase = xbf + ((size_t)b * NPK + tok) * Cc + kg * 8;
  const unsigned short* bbase = wqb + (size_t)(nt * 16 + m) * Cc + kg * 8;
  f32x4 acc = {0, 0, 0, 0};
  for (int k0 = 0; k0 < Cc; k0 += 32) {
    short8 a = *(const short8*)(abase + k0);
    short8 bf = *(const short8*)(bbase + k0);
    acc = __builtin_amdgcn_mfma_f32_16x16x32_bf16(a, bf, acc, 0, 0, 0);
  }
  int c = nt * 16 + m;
  #pragma unroll
  for (int r = 0; r < 4; r++) {
    int rowo = mt * 16 + kg * 4 + r;
    qb[(size_t)rowo * Cc + c] = f2bf(acc[r]);
  }
}

// ---------------- K9: u for gathered rows via MFMA ----------------
__global__ __launch_bounds__(256) void k_ug_mfma(
    const unsigned short* __restrict__ qb, const unsigned short* __restrict__ wkTb,
    unsigned short* __restrict__ u16b) {
  int h = blockIdx.x, mt = blockIdx.y, ngz = blockIdx.z;
  int wid = threadIdx.x >> 6, lane = threadIdx.x & 63;
  int m = lane & 15, kg = lane >> 4;
  int rowi = mt * 16 + m;
  const unsigned short* abase = qb + (size_t)rowi * Cc + h * HD + kg * 8;
  f32x4 acc[4] = {{0,0,0,0},{0,0,0,0},{0,0,0,0},{0,0,0,0}};
  #pragma unroll
  for (int k0 = 0; k0 < HD; k0 += 32) {
    short8 a = *(const short8*)(abase + k0);
    #pragma unroll
    for (int t = 0; t < 4; t++) {
      int c = ngz * 256 + (wid * 4 + t) * 16 + m;
      short8 bf = *(const short8*)(wkTb + (size_t)c * Cc + h * HD + kg * 8 + k0);
      acc[t] = __builtin_amdgcn_mfma_f32_16x16x32_bf16(a, bf, acc[t], 0, 0, 0);
    }
  }
  #pragma unroll
  for (int t = 0; t < 4; t++) {
    int c = ngz * 256 + (wid * 4 + t) * 16 + m;
    #pragma unroll
    for (int r = 0; r < 4; r++) {
      int row = mt * 16 + kg * 4 + r;
      int b = row >> 4, s = row & 15;
      u16b[((size_t)b * 192 + s * Hh + h) * Cc + c] = f2bf(acc[t][r]);
    }
  }
}

// ---------------- K10: gathered logits via MFMA, LDS-staged B ----------------
// grid (Bn, 3, 9): b, mg (64 rows), nz (128 j-cols). 4 waves 2x2:
// wave (wm,wn): rows mg*64+wm*32 (2 m-tiles), cols wn*64 (4 n-tiles).
__global__ __launch_bounds__(256) void k_glogits_mfma(
    const unsigned short* __restrict__ u16b, const unsigned short* __restrict__ xbf,
    float* __restrict__ S) {
  int b = blockIdx.x, mg = blockIdx.y, nz = blockIdx.z;
  __shared__ __align__(16) unsigned short Bs[2][128 * 32];
  int t = threadIdx.x, w = t >> 6, lane = t & 63;
  int wm = w >> 1, wn = w & 1;
  int m = lane & 15, kg = lane >> 4;
  int r0 = mg * 64 + wm * 32 + m;
  const unsigned short* a0p = u16b + ((size_t)b * 192 + r0) * Cc + kg * 8;
  const unsigned short* a1p = a0p + (size_t)16 * Cc;
  // staging: wave w stages cols w*32 .. w*32+31 (2 groups of 16)
  int scol = lane >> 2;
  int skp = (lane & 3) * 8;
  const unsigned short* gB0 = xbf + ((size_t)b * NPK + nz * 128 + w * 32 + scol) * Cc + skp;
  const unsigned short* gB1 = gB0 + (size_t)16 * Cc;
  int lo0 = (w * 32 + scol) * 32 + skp;
  int lo1 = lo0 + 16 * 32;
  constexpr int NIT = Cc / 32;  // 24
  short8 s0 = *(const short8*)(gB0);
  short8 s1 = *(const short8*)(gB1);
  *(short8*)&Bs[0][lo0] = s0;
  *(short8*)&Bs[0][lo1] = s1;
  __syncthreads();
  f32x4 acc[2][4] = {};
  for (int it = 0; it < NIT; it++) {
    int k0 = it * 32;
    int cur = it & 1;
    short8 n0, n1;
    if (it + 1 < NIT) {
      n0 = *(const short8*)(gB0 + k0 + 32);
      n1 = *(const short8*)(gB1 + k0 + 32);
    }
    short8 a0 = *(const short8*)(a0p + k0);
    short8 a1 = *(const short8*)(a1p + k0);
    #pragma unroll
    for (int tt = 0; tt < 4; tt++) {
      int col = wn * 64 + tt * 16 + m;
      short8 bf = *(const short8*)&Bs[cur][col * 32 + kg * 8];
      acc[0][tt] = __builtin_amdgcn_mfma_f32_16x16x32_bf16(a0, bf, acc[0][tt], 0, 0, 0);
      acc[1][tt] = __builtin_amdgcn_mfma_f32_16x16x32_bf16(a1, bf, acc[1][tt], 0, 0, 0);
    }
    if (it + 1 < NIT) {
      *(short8*)&Bs[cur ^ 1][lo0] = n0;
      *(short8*)&Bs[cur ^ 1][lo1] = n1;
    }
    __syncthreads();
  }
  #pragma unroll
  for (int mt = 0; mt < 2; mt++) {
    #pragma unroll
    for (int tt = 0; tt < 4; tt++) {
      int col = nz * 128 + wn * 64 + tt * 16 + m;
      #pragma unroll
      for (int r = 0; r < 4; r++) {
        int row = mg * 64 + wm * 32 + mt * 16 + kg * 4 + r;
        S[((size_t)b * 192 + row) * NPK + col] = acc[mt][tt][r] * 0.125f;
      }
    }
  }
}

// ---------------- K11: softmax for gathered rows (reads S, writes bf16 P) --
__global__ __launch_bounds__(256) void k_gsoftmax(
    const float* __restrict__ S, unsigned short* __restrict__ Pb) {
  int blk = blockIdx.x;
  int b = blk / 192, r = blk % 192;
  const float* row = S + ((size_t)b * 192 + r) * NPK;
  unsigned short* prow = Pb + ((size_t)b * 216 + 24 + r) * NPK;
  int t = threadIdx.x;
  __shared__ float sd[256];
  float mx = -1e30f;
  for (int j = t; j < Nn; j += 256) mx = fmaxf(mx, row[j]);
  sd[t] = mx; __syncthreads();
  for (int st = 128; st > 0; st >>= 1) { if (t < st) sd[t] = fmaxf(sd[t], sd[t + st]); __syncthreads(); }
  mx = sd[0]; __syncthreads();
  float sum = 0;
  for (int j = t; j < Nn; j += 256) sum += __expf(row[j] - mx);
  sd[t] = sum; __syncthreads();
  for (int st = 128; st > 0; st >>= 1) { if (t < st) sd[t] += sd[t + st]; __syncthreads(); }
  float inv = 1.0f / sd[0];
  for (int j = t; j < NPK; j += 256) {
    prow[j] = (j < Nn) ? f2bf(__expf(row[j] - mx) * inv) : (unsigned short)0;
  }
}

// ---------------- K12: wsum via MFMA, LDS-staged B ----------------
// grid (Bn, 4, 6): b, mg (64 rows of 216+pad), nz (128 c-cols). Waves 2x2.
__global__ __launch_bounds__(256) void k_wsum_mfma(
    const unsigned short* __restrict__ Pb, const unsigned short* __restrict__ xT,
    unsigned short* __restrict__ wsumb) {
  int b = blockIdx.x, mg = blockIdx.y, nz = blockIdx.z;
  __shared__ __align__(16) unsigned short Bs[2][128 * 32];
  int t = threadIdx.x, w = t >> 6, lane = t & 63;
  int wm = w >> 1, wn = w & 1;
  int m = lane & 15, kg = lane >> 4;
  int r0 = mg * 64 + wm * 32 + m;
  int rc0 = r0 < 216 ? r0 : 215;
  int rc1 = (r0 + 16) < 216 ? (r0 + 16) : 215;
  const unsigned short* a0p = Pb + ((size_t)b * 216 + rc0) * NPK + kg * 8;
  const unsigned short* a1p = Pb + ((size_t)b * 216 + rc1) * NPK + kg * 8;
  int scol = lane >> 2;
  int skp = (lane & 3) * 8;
  const unsigned short* gB0 = xT + ((size_t)b * Cc + nz * 128 + w * 32 + scol) * NPK + skp;
  const unsigned short* gB1 = gB0 + (size_t)16 * NPK;
  int lo0 = (w * 32 + scol) * 32 + skp;
  int lo1 = lo0 + 16 * 32;
  constexpr int NIT = NPK / 32;  // 36
  short8 s0 = *(const short8*)(gB0);
  short8 s1 = *(const short8*)(gB1);
  *(short8*)&Bs[0][lo0] = s0;
  *(short8*)&Bs[0][lo1] = s1;
  __syncthreads();
  f32x4 acc[2][4] = {};
  for (int it = 0; it < NIT; it++) {
    int k0 = it * 32;
    int cur = it & 1;
    short8 n0, n1;
    if (it + 1 < NIT) {
      n0 = *(const short8*)(gB0 + k0 + 32);
      n1 = *(const short8*)(gB1 + k0 + 32);
    }
    short8 a0 = *(const short8*)(a0p + k0);
    short8 a1 = *(const short8*)(a1p + k0);
    #pragma unroll
    for (int tt = 0; tt < 4; tt++) {
      int col = wn * 64 + tt * 16 + m;
      short8 bf = *(const short8*)&Bs[cur][col * 32 + kg * 8];
      acc[0][tt] = __builtin_amdgcn_mfma_f32_16x16x32_bf16(a0, bf, acc[0][tt], 0, 0, 0);
      acc[1][tt] = __builtin_amdgcn_mfma_f32_16x16x32_bf16(a1, bf, acc[1][tt], 0, 0, 0);
    }
    if (it + 1 < NIT) {
      *(short8*)&Bs[cur ^ 1][lo0] = n0;
      *(short8*)&Bs[cur ^ 1][lo1] = n1;
    }
    __syncthreads();
  }
  #pragma unroll
  for (int mt = 0; mt < 2; mt++) {
    #pragma unroll
    for (int tt = 0; tt < 4; tt++) {
      int col = nz * 128 + wn * 64 + tt * 16 + m;
      #pragma unroll
      for (int r = 0; r < 4; r++) {
        int row = mg * 64 + wm * 32 + mt * 16 + kg * 4 + r;
        if (row < 216) wsumb[((size_t)b * 216 + row) * Cc + col] = f2bf(acc[mt][tt][r]);
      }
    }
  }
}

// ---------------- K13: attnout = Wv * wsum via MFMA ----------------
__global__ __launch_bounds__(256) void k_attnout_mfma(
    const unsigned short* __restrict__ wsumb, const unsigned short* __restrict__ wvb,
    unsigned short* __restrict__ aob) {
  int h = blockIdx.x, mt = blockIdx.y;
  int wid = threadIdx.x >> 6, lane = threadIdx.x & 63;
  int m = lane & 15, kg = lane >> 4;
  int row = mt * 16 + m;
  int b = row / NR, i = row % NR;
  const unsigned short* abase = wsumb + ((size_t)b * 216 + i * 12 + h) * Cc + kg * 8;
  const unsigned short* bbase = wvb + (size_t)(h * HD + wid * 16 + m) * Cc + kg * 8;
  f32x4 acc = {0, 0, 0, 0};
  for (int k0 = 0; k0 < Cc; k0 += 32) {
    short8 a = *(const short8*)(abase + k0);
    short8 bf = *(const short8*)(bbase + k0);
    acc = __builtin_amdgcn_mfma_f32_16x16x32_bf16(a, bf, acc, 0, 0, 0);
  }
  #pragma unroll
  for (int r = 0; r < 4; r++) {
    int orow = mt * 16 + kg * 4 + r;
    int ocol = h * HD + wid * 16 + m;
    aob[(size_t)orow * Cc + ocol] = f2bf(acc[r]);
  }
}

// ---------------- K14: proj via MFMA + bias + residual + scatter ----------
__global__ __launch_bounds__(256) void k_proj_mfma(
    const unsigned short* __restrict__ aob, const unsigned short* __restrict__ wpb,
    const float* __restrict__ bproj, const int* __restrict__ rowcat,
    const float* __restrict__ gen, const float* __restrict__ cls,
    const float* __restrict__ box, float* __restrict__ out) {
  int mt = blockIdx.x, ng = blockIdx.y;
  int wid = threadIdx.x >> 6, lane = threadIdx.x & 63;
  int nt = ng * 4 + wid;
  int m = lane & 15, kg = lane >> 4;
  const unsigned short* abase = aob + (size_t)(mt * 16 + m) * Cc + kg * 8;
  const unsigned short* bbase = wpb + (size_t)(nt * 16 + m) * Cc + kg * 8;
  f32x4 acc = {0, 0, 0, 0};
  for (int k0 = 0; k0 < Cc; k0 += 32) {
    short8 a = *(const short8*)(abase + k0);
    short8 bf = *(const short8*)(bbase + k0);
    acc = __builtin_amdgcn_mfma_f32_16x16x32_bf16(a, bf, acc, 0, 0, 0);
  }
  int c = nt * 16 + m;
  float bp = bproj[c];
  #pragma unroll
  for (int r = 0; r < 4; r++) {
    int bi = mt * 16 + kg * 4 + r;
    int b = bi / NR, i = bi % NR;
    int tok = rowcat[b * NR + i];
    const float* src = (tok == 0) ? cls + (size_t)b * Cc
                     : (tok == 1) ? box + (size_t)b * Cc
                                  : gen + ((size_t)b * NG + tok - 2) * Cc;
    float val = acc[r] + bp + src[c];
    float* dst;
    if (i == 0)       dst = out + ((size_t)b * 9 + 0) * Cc;
    else if (i == 1)  dst = out + (size_t)Bn * 9 * Cc + ((size_t)b * 9 + 0) * Cc;
    else if (i < 10)  dst = out + ((size_t)b * 9 + (i - 1)) * Cc;
    else              dst = out + (size_t)Bn * 9 * Cc + ((size_t)b * 9 + (i - 9)) * Cc;
    dst[c] = val;
  }
}

}  // namespace

extern "C" void kernel_launch(void* const* d_in, const int* in_sizes, int n_in,
                              void* d_out, int out_size, void* d_ws, size_t ws_size,
                              hipStream_t stream) {
  (void)in_sizes; (void)n_in; (void)out_size; (void)ws_size;
  const float* gen   = (const float*)d_in[0];
  const float* cls   = (const float*)d_in[1];
  const float* box   = (const float*)d_in[2];
  const float* wqkv  = (const float*)d_in[3];
  const float* wproj = (const float*)d_in[4];
  const float* bproj = (const float*)d_in[5];
  const float* gamma = (const float*)d_in[6];
  const float* beta  = (const float*)d_in[7];
  float* out = (float*)d_out;

  char* ws = (char*)d_ws;
  size_t off = 0;
  auto alloc = [&](size_t bytes) { void* p = ws + off; off += (bytes + 255) & ~(size_t)255; return p; };
  float* x             = (float*)alloc((size_t)Bn * Nn * Cc * 4);
  unsigned short* xbf  = (unsigned short*)alloc((size_t)Bn * NPK * Cc * 2);
  unsigned short* xT   = (unsigned short*)alloc((size_t)Bn * Cc * NPK * 2);
  unsigned short* qb   = (unsigned short*)alloc((size_t)256 * Cc * 2);
  unsigned short* u16b = (unsigned short*)alloc((size_t)Bn * 192 * Cc * 2);
  float* S             = (float*)alloc((size_t)Bn * 192 * NPK * 4);
  unsigned short* Pb   = (unsigned short*)alloc((size_t)Bn * 216 * NPK * 2);
  unsigned short* wsumb= (unsigned short*)alloc((size_t)Bn * 216 * Cc * 2);
  unsigned short* aob  = (unsigned short*)alloc((size_t)288 * Cc * 2);
  unsigned short* wqb  = (unsigned short*)alloc((size_t)Cc * Cc * 2);
  unsigned short* wvb  = (unsigned short*)alloc((size_t)Cc * Cc * 2);
  unsigned short* wpb  = (unsigned short*)alloc((size_t)Cc * Cc * 2);
  unsigned short* wkTb = (unsigned short*)alloc((size_t)Cc * Cc * 2);
  double* q01d         = (double*)alloc((size_t)Bn * 2 * Cc * 8);
  double* u01d         = (double*)alloc((size_t)Bn * 2 * Hh * Cc * 8);
  double* Ld           = (double*)alloc((size_t)Bn * 2 * Hh * Nn * 8);
  double* Ldp          = (double*)alloc((size_t)NCH * Bn * 24 * Nn * 8);
  double* suma         = (double*)alloc((size_t)Bn * NG * 8);
  double* diffd        = (double*)alloc((size_t)Bn * NG * 8);
  int* rowcat          = (int*)alloc((size_t)Bn * NR * 4);

  k_ln<<<Bn * Nn, 256, 0, stream>>>(gen, cls, box, gamma, beta, x, xbf);
  k_padzero<<<96, 256, 0, stream>>>(xbf);
  k_xt<<<dim3(Bn, NPK / 64, Cc / 64), 256, 0, stream>>>(xbf, xT);
  k_wcvt<<<(Cc * Cc / 4 + 255) / 256, 256, 0, stream>>>(wqkv, wproj, wqb, wvb, wpb);
  k_wkt<<<dim3(12, 12), 256, 0, stream>>>(wqkv, wkTb);
  k_q01<<<dim3(Bn * 2, 192), 256, 0, stream>>>(wqkv, x, q01d);
  k_u01<<<dim3(Bn * 2 * Hh, 3), 256, 0, stream>>>(wqkv, q01d, u01d);
  k_rlogits<<<dim3(Bn, 5, NCH), 256, 0, stream>>>(u01d, x, Ldp);
  k_rsoftmax<<<Bn * 2 * Hh, 256, 0, stream>>>(Ldp, Ld, Pb);
  k_rsums<<<Bn, 256, 0, stream>>>(Ld, suma, diffd);
  k_route<<<Bn, 256, 0, stream>>>(suma, diffd, rowcat);
  k_qg_mfma<<<dim3(16, 12), 256, 0, stream>>>(xbf, wqb, rowcat, qb);
  k_ug_mfma<<<dim3(Hh, 16, 3), 256, 0, stream>>>(qb, wkTb, u16b);
  k_glogits_mfma<<<dim3(Bn, 3, 9), 256, 0, stream>>>(u16b, xbf, S);
  k_gsoftmax<<<Bn * 192, 256, 0, stream>>>(S, Pb);
  k_wsum_mfma<<<dim3(Bn, 4, 6), 256, 0, stream>>>(Pb, xT, wsumb);
  k_attnout_mfma<<<dim3(Hh, 18), 256, 0, stream>>>(wsumb, wvb, aob);
  k_proj_mfma<<<dim3(18, 12), 256, 0, stream>>>(aob, wpb, bproj, rowcat, gen, cls, box, out);
}